// Round 6
// baseline (7693.276 us; speedup 1.0000x reference)
//
#include <hip/hip_runtime.h>
#include <math.h>

#define NBLK 1024   // 4 blocks/CU x 256 CUs — co-residency by construction
#define NTHR 256

static inline int ceil_div_h(int a, int b) { return (a + b - 1) / b; }

// ---------------------------------------------------------------------------
// Grid-wide barrier: generation-based, device-scope atomics + __threadfence
// (release writes / acquire-invalidate L1). All NBLK blocks are co-resident
// (__launch_bounds__(256,4) caps VGPR<=128; LDS 17.4KB -> 4 blocks/CU fit).
// ---------------------------------------------------------------------------
__device__ __forceinline__ void gsync(int* __restrict__ ctl) {
    __syncthreads();
    if (threadIdx.x == 0) {
        __threadfence();
        int g = __hip_atomic_load(&ctl[1], __ATOMIC_RELAXED, __HIP_MEMORY_SCOPE_AGENT);
        int a = __hip_atomic_fetch_add(&ctl[0], 1, __ATOMIC_ACQ_REL, __HIP_MEMORY_SCOPE_AGENT);
        if (a == NBLK - 1) {
            __hip_atomic_store(&ctl[0], 0, __ATOMIC_RELAXED, __HIP_MEMORY_SCOPE_AGENT);
            __hip_atomic_fetch_add(&ctl[1], 1, __ATOMIC_RELEASE, __HIP_MEMORY_SCOPE_AGENT);
        } else {
            while (__hip_atomic_load(&ctl[1], __ATOMIC_ACQUIRE, __HIP_MEMORY_SCOPE_AGENT) == g)
                __builtin_amdgcn_s_sleep(2);
        }
        __threadfence();
    }
    __syncthreads();
}

// Work-stealing tile grab (uniform across block via LDS broadcast).
__device__ __forceinline__ int grab(int* ctr, int* tshp) {
    if (threadIdx.x == 0) *tshp = atomicAdd(ctr, 1);
    __syncthreads();
    int v = *tshp;
    __syncthreads();
    return v;
}

// ---------------------------------------------------------------------------
// Tile bodies (device functions). smem layout: As = smem (16x68 floats),
// Bs = smem + 1088 (16x200 for conv1, 16x68 otherwise).
// ---------------------------------------------------------------------------

// conv1: rows [tile*64, +64) of C[n,192] = x[n,256] @ Bc1[256,192].
// Micro 4x12. Split epilogue: cols 0..127 -> yz, 128..191 -> base + b1.
__device__ __forceinline__ void conv1_tile(
    int tile, int n, const float* __restrict__ x, const float* __restrict__ B,
    float* __restrict__ yz, float* __restrict__ base, const float* __restrict__ b1,
    float* As, float* Bs) {
    const int t = threadIdx.x;
    const int row0 = tile * 64;
    const int ty = t >> 4, tx = t & 15;
    const int lrow = t >> 2, lk = (t & 3) << 2;
    const int bkk = t >> 4, bcol = (t & 15) << 2;
    float acc[4][12];
    #pragma unroll
    for (int i = 0; i < 4; ++i)
        #pragma unroll
        for (int j = 0; j < 12; ++j) acc[i][j] = 0.f;

    for (int kt = 0; kt < 16; ++kt) {
        int k0 = kt << 4;
        float4 av = make_float4(0.f, 0.f, 0.f, 0.f);
        int r = row0 + lrow;
        if (r < n) av = *reinterpret_cast<const float4*>(&x[(size_t)r * 256 + k0 + lk]);
        const float* bp = &B[(size_t)(k0 + bkk) * 192 + bcol];
        float4 bv0 = *reinterpret_cast<const float4*>(bp);
        float4 bv1 = *reinterpret_cast<const float4*>(bp + 64);
        float4 bv2 = *reinterpret_cast<const float4*>(bp + 128);
        As[(lk + 0) * 68 + lrow] = av.x; As[(lk + 1) * 68 + lrow] = av.y;
        As[(lk + 2) * 68 + lrow] = av.z; As[(lk + 3) * 68 + lrow] = av.w;
        *reinterpret_cast<float4*>(&Bs[bkk * 200 + bcol])       = bv0;
        *reinterpret_cast<float4*>(&Bs[bkk * 200 + bcol + 64])  = bv1;
        *reinterpret_cast<float4*>(&Bs[bkk * 200 + bcol + 128]) = bv2;
        __syncthreads();
        #pragma unroll
        for (int kk = 0; kk < 16; ++kk) {
            float4 a4 = *reinterpret_cast<const float4*>(&As[kk * 68 + (ty << 2)]);
            float4 b0 = *reinterpret_cast<const float4*>(&Bs[kk * 200 + (tx << 2)]);
            float4 b1v = *reinterpret_cast<const float4*>(&Bs[kk * 200 + (tx << 2) + 64]);
            float4 b2v = *reinterpret_cast<const float4*>(&Bs[kk * 200 + (tx << 2) + 128]);
            float aa[4] = {a4.x, a4.y, a4.z, a4.w};
            float bb[12] = {b0.x, b0.y, b0.z, b0.w, b1v.x, b1v.y, b1v.z, b1v.w,
                            b2v.x, b2v.y, b2v.z, b2v.w};
            #pragma unroll
            for (int i = 0; i < 4; ++i)
                #pragma unroll
                for (int j = 0; j < 12; ++j)
                    acc[i][j] = fmaf(aa[i], bb[j], acc[i][j]);
        }
        __syncthreads();
    }

    float4 bb4 = *reinterpret_cast<const float4*>(&b1[tx << 2]);
    #pragma unroll
    for (int i = 0; i < 4; ++i) {
        int r = row0 + (ty << 2) + i;
        if (r >= n) continue;
        float4 q0 = make_float4(acc[i][0], acc[i][1], acc[i][2], acc[i][3]);
        float4 q1 = make_float4(acc[i][4], acc[i][5], acc[i][6], acc[i][7]);
        float4 q2 = make_float4(acc[i][8] + bb4.x, acc[i][9] + bb4.y,
                                acc[i][10] + bb4.z, acc[i][11] + bb4.w);
        *reinterpret_cast<float4*>(&yz[(size_t)r * 128 + (tx << 2)]) = q0;
        *reinterpret_cast<float4*>(&yz[(size_t)r * 128 + 64 + (tx << 2)]) = q1;
        *reinterpret_cast<float4*>(&base[(size_t)r * 64 + (tx << 2)]) = q2;
    }
}

// Hidden SplineConv tile: block-local agg (64 rows -> aggbuf global scratch,
// same-CU write->read coherent after __syncthreads) then GEMM
// [agg|in][64,192] @ B[192,64].
//   mode 0: u_out = A@B + bias
//   mode 1: v = A@B+bias; an = acc_in + c3*v; acc_out = an;
//           t_out = hbuf + c1*v + c2*an   (acc_in==null -> 0)
__device__ __forceinline__ void hidden_tile(
    int tile, int n, const float* __restrict__ in,
    const int* __restrict__ rowp, const int* __restrict__ es,
    const float* __restrict__ ep, const float* __restrict__ invd,
    const float* __restrict__ B, const float* __restrict__ bias,
    float* __restrict__ aggbuf, int mode, float* __restrict__ u_out,
    const float* __restrict__ hbuf, const float* __restrict__ acc_in,
    float* __restrict__ acc_out, float* __restrict__ t_out,
    float c1, float c2, float c3, float* As, float* Bs) {
    const int t = threadIdx.x;
    const int row0 = tile * 64;
    const int c4 = (t & 15) << 2;
    const int ng = t >> 4;

    // ---- gather/aggregate: 4 sub-rounds x 16 nodes, 16 lanes x float4 ----
    for (int sub = 0; sub < 4; ++sub) {
        int node = row0 + (sub << 4) + ng;
        if (node >= n) continue;
        int e = rowp[node], eend = rowp[node + 1];
        float sx = 0.f, sy = 0.f, sz = 0.f, sw = 0.f;
        float px = 0.f, py = 0.f, pz = 0.f, pw = 0.f;
        for (; e + 4 <= eend; e += 4) {
            int a = es[e], b = es[e + 1], c = es[e + 2], d = es[e + 3];
            float pa = ep[e], pb = ep[e + 1], pc = ep[e + 2], pd = ep[e + 3];
            float4 va = *reinterpret_cast<const float4*>(&in[(size_t)a * 64 + c4]);
            float4 vb = *reinterpret_cast<const float4*>(&in[(size_t)b * 64 + c4]);
            float4 vc = *reinterpret_cast<const float4*>(&in[(size_t)c * 64 + c4]);
            float4 vd = *reinterpret_cast<const float4*>(&in[(size_t)d * 64 + c4]);
            sx += (va.x + vb.x) + (vc.x + vd.x);
            sy += (va.y + vb.y) + (vc.y + vd.y);
            sz += (va.z + vb.z) + (vc.z + vd.z);
            sw += (va.w + vb.w) + (vc.w + vd.w);
            px = fmaf(pa, va.x, fmaf(pb, vb.x, fmaf(pc, vc.x, fmaf(pd, vd.x, px))));
            py = fmaf(pa, va.y, fmaf(pb, vb.y, fmaf(pc, vc.y, fmaf(pd, vd.y, py))));
            pz = fmaf(pa, va.z, fmaf(pb, vb.z, fmaf(pc, vc.z, fmaf(pd, vd.z, pz))));
            pw = fmaf(pa, va.w, fmaf(pb, vb.w, fmaf(pc, vc.w, fmaf(pd, vd.w, pw))));
        }
        for (; e < eend; ++e) {
            int s = es[e];
            float pe = ep[e];
            float4 v = *reinterpret_cast<const float4*>(&in[(size_t)s * 64 + c4]);
            sx += v.x; sy += v.y; sz += v.z; sw += v.w;
            px = fmaf(pe, v.x, px); py = fmaf(pe, v.y, py);
            pz = fmaf(pe, v.z, pz); pw = fmaf(pe, v.w, pw);
        }
        float w = invd[node];
        float4 a0 = make_float4((sx - px) * w, (sy - py) * w,
                                (sz - pz) * w, (sw - pw) * w);
        float4 a1 = make_float4(px * w, py * w, pz * w, pw * w);
        *reinterpret_cast<float4*>(&aggbuf[(size_t)node * 128 + c4]) = a0;
        *reinterpret_cast<float4*>(&aggbuf[(size_t)node * 128 + 64 + c4]) = a1;
    }
    __syncthreads();  // aggbuf writes visible block-locally (same CU)

    // ---- GEMM: [64 x 192] @ [192 x 64], micro 4x4 ----
    const int ty = t >> 4, tx = t & 15;
    const int lrow = t >> 2, lk = (t & 3) << 2;
    const int bkk = t >> 4, bcol = (t & 15) << 2;
    float acc[4][4];
    #pragma unroll
    for (int i = 0; i < 4; ++i)
        #pragma unroll
        for (int j = 0; j < 4; ++j) acc[i][j] = 0.f;

    for (int kt = 0; kt < 12; ++kt) {
        int k0 = kt << 4;
        int kk0 = k0 + lk;
        float4 av = make_float4(0.f, 0.f, 0.f, 0.f);
        int r = row0 + lrow;
        if (r < n)
            av = (kk0 < 128)
                ? *reinterpret_cast<const float4*>(&aggbuf[(size_t)r * 128 + kk0])
                : *reinterpret_cast<const float4*>(&in[(size_t)r * 64 + (kk0 - 128)]);
        float4 bv = *reinterpret_cast<const float4*>(&B[(size_t)(k0 + bkk) * 64 + bcol]);
        As[(lk + 0) * 68 + lrow] = av.x; As[(lk + 1) * 68 + lrow] = av.y;
        As[(lk + 2) * 68 + lrow] = av.z; As[(lk + 3) * 68 + lrow] = av.w;
        *reinterpret_cast<float4*>(&Bs[bkk * 68 + bcol]) = bv;
        __syncthreads();
        #pragma unroll
        for (int kk = 0; kk < 16; ++kk) {
            float4 a4 = *reinterpret_cast<const float4*>(&As[kk * 68 + (ty << 2)]);
            float4 b4 = *reinterpret_cast<const float4*>(&Bs[kk * 68 + (tx << 2)]);
            float aa[4] = {a4.x, a4.y, a4.z, a4.w};
            float bb[4] = {b4.x, b4.y, b4.z, b4.w};
            #pragma unroll
            for (int i = 0; i < 4; ++i)
                #pragma unroll
                for (int j = 0; j < 4; ++j)
                    acc[i][j] = fmaf(aa[i], bb[j], acc[i][j]);
        }
        __syncthreads();
    }

    float4 bia = *reinterpret_cast<const float4*>(&bias[tx << 2]);
    #pragma unroll
    for (int i = 0; i < 4; ++i) {
        int r = row0 + (ty << 2) + i;
        if (r >= n) continue;
        size_t idx = (size_t)r * 64 + (tx << 2);
        float4 v = make_float4(acc[i][0] + bia.x, acc[i][1] + bia.y,
                               acc[i][2] + bia.z, acc[i][3] + bia.w);
        if (mode == 0) {
            *reinterpret_cast<float4*>(&u_out[idx]) = v;
        } else {
            float4 ai = make_float4(0.f, 0.f, 0.f, 0.f);
            if (acc_in) ai = *reinterpret_cast<const float4*>(&acc_in[idx]);
            float4 an = make_float4(ai.x + c3 * v.x, ai.y + c3 * v.y,
                                    ai.z + c3 * v.z, ai.w + c3 * v.w);
            *reinterpret_cast<float4*>(&acc_out[idx]) = an;
            float4 hb = *reinterpret_cast<const float4*>(&hbuf[idx]);
            float4 to = make_float4(hb.x + c1 * v.x + c2 * an.x,
                                    hb.y + c1 * v.y + c2 * an.y,
                                    hb.z + c1 * v.z + c2 * an.z,
                                    hb.w + c1 * v.w + c2 * an.w);
            *reinterpret_cast<float4*>(&t_out[idx]) = to;
        }
    }
}

// conv2 tile: C[64,48] = tb[64,64] @ Bc2[64,48]; cols 0..31 -> yz2(w=32),
// 32..47 -> base2(w=16)+b2.
__device__ __forceinline__ void conv2_tile(
    int tile, int n, const float* __restrict__ A, const float* __restrict__ B,
    float* __restrict__ yz2, float* __restrict__ base2, const float* __restrict__ b2,
    float* As, float* Bs) {
    const int t = threadIdx.x;
    const int row0 = tile * 64;
    const int ty = t >> 4, tx = t & 15;
    const int lrow = t >> 2, lk = (t & 3) << 2;
    const int bkk = t >> 4, bcol = (t & 15) << 2;
    float acc[4][4];
    #pragma unroll
    for (int i = 0; i < 4; ++i)
        #pragma unroll
        for (int j = 0; j < 4; ++j) acc[i][j] = 0.f;

    for (int kt = 0; kt < 4; ++kt) {
        int k0 = kt << 4;
        float4 av = make_float4(0.f, 0.f, 0.f, 0.f);
        int r = row0 + lrow;
        if (r < n) av = *reinterpret_cast<const float4*>(&A[(size_t)r * 64 + k0 + lk]);
        As[(lk + 0) * 68 + lrow] = av.x; As[(lk + 1) * 68 + lrow] = av.y;
        As[(lk + 2) * 68 + lrow] = av.z; As[(lk + 3) * 68 + lrow] = av.w;
        if (bcol < 48) {
            float4 bv = *reinterpret_cast<const float4*>(&B[(size_t)(k0 + bkk) * 48 + bcol]);
            *reinterpret_cast<float4*>(&Bs[bkk * 68 + bcol]) = bv;
        }
        __syncthreads();
        if (tx < 12) {
            #pragma unroll
            for (int kk = 0; kk < 16; ++kk) {
                float4 a4 = *reinterpret_cast<const float4*>(&As[kk * 68 + (ty << 2)]);
                float4 b4 = *reinterpret_cast<const float4*>(&Bs[kk * 68 + (tx << 2)]);
                float aa[4] = {a4.x, a4.y, a4.z, a4.w};
                float bb[4] = {b4.x, b4.y, b4.z, b4.w};
                #pragma unroll
                for (int i = 0; i < 4; ++i)
                    #pragma unroll
                    for (int j = 0; j < 4; ++j)
                        acc[i][j] = fmaf(aa[i], bb[j], acc[i][j]);
            }
        }
        __syncthreads();
    }

    if (tx < 12) {
        #pragma unroll
        for (int i = 0; i < 4; ++i) {
            int r = row0 + (ty << 2) + i;
            if (r >= n) continue;
            #pragma unroll
            for (int j = 0; j < 4; ++j) {
                int c = (tx << 2) + j;
                float v = acc[i][j];
                if (c < 32) yz2[(size_t)r * 32 + c] = v;
                else        base2[(size_t)r * 16 + (c - 32)] = v + b2[c - 32];
            }
        }
    }
}

// ---------------------------------------------------------------------------
// The persistent mega-kernel: setup + conv1 + RK4 + conv2 + log_softmax,
// 18 grid barriers, work-stealing tiles (ctl[2..11]).
// ---------------------------------------------------------------------------
__global__ __launch_bounds__(NTHR, 4) void mega(
    const float* __restrict__ x, const float* __restrict__ pE,
    const int* __restrict__ sr, const int* __restrict__ ds,
    const float* __restrict__ W1, const float* __restrict__ R1,
    const float* __restrict__ b1,
    const float* __restrict__ Wa, const float* __restrict__ Ra,
    const float* __restrict__ ba,
    const float* __restrict__ Wb, const float* __restrict__ Rb,
    const float* __restrict__ bbv,
    const float* __restrict__ W2, const float* __restrict__ R2,
    const float* __restrict__ b2,
    int n, int E,
    int* __restrict__ ctl, int* __restrict__ deg, int* __restrict__ fill,
    int* __restrict__ rowp, float* __restrict__ invd, int* __restrict__ bsum,
    int* __restrict__ ei, int* __restrict__ es, float* __restrict__ ep,
    float* __restrict__ Bc1, float* __restrict__ Bca, float* __restrict__ Bcb,
    float* __restrict__ Bc2,
    float* __restrict__ big0, float* __restrict__ big1, float* __restrict__ h,
    float* __restrict__ u, float* __restrict__ tb, float* __restrict__ rk,
    float* __restrict__ out) {
    __shared__ __align__(16) float smem[4352];   // As(16x68) + Bs(16x200)
    __shared__ int tsh;
    float* As = smem;
    float* Bs = smem + 1088;
    const int t = threadIdx.x;
    const int bid = blockIdx.x;
    const int gid = bid * NTHR + t;
    const int gstride = NBLK * NTHR;
    const int ntiles = (n + 63) >> 6;
    const int nscan = (n + 2047) >> 11;

    // ---- P0: zero deg/fill + pack weights ----
    for (int i = gid; i < n; i += gstride) { deg[i] = 0; fill[i] = 0; }
    {
        const int S1 = 256 * 192, S2 = 192 * 64, S4 = 64 * 48;
        const int TOT = S1 + 2 * S2 + S4;
        for (int i0 = gid; i0 < TOT; i0 += gstride) {
            int idx = i0;
            if (idx < S1) {
                int k = idx / 192, c = idx % 192;
                float v;
                if (c < 64)       v = W1[k * 64 + c];
                else if (c < 128) v = W1[256 * 64 + k * 64 + (c - 64)];
                else              v = R1[k * 64 + (c - 128)];
                Bc1[idx] = v;
                continue;
            }
            idx -= S1;
            if (idx < S2) { Bca[idx] = (idx < 8192) ? Wa[idx] : Ra[idx - 8192]; continue; }
            idx -= S2;
            if (idx < S2) { Bcb[idx] = (idx < 8192) ? Wb[idx] : Rb[idx - 8192]; continue; }
            idx -= S2;
            int k = idx / 48, c = idx % 48;
            float v;
            if (c < 16)      v = W2[k * 16 + c];
            else if (c < 32) v = W2[64 * 16 + k * 16 + (c - 16)];
            else             v = R2[k * 16 + (c - 32)];
            Bc2[idx] = v;
        }
    }
    gsync(ctl);

    // ---- P1: degree histogram ----
    for (int e = gid; e < E; e += gstride) atomicAdd(&deg[ds[e]], 1);
    gsync(ctl);

    // ---- P2: per-chunk (2048) block sums ----
    if (bid < nscan) {
        int* red = (int*)smem;
        int base = bid * 2048 + t * 8;
        int s = 0;
        #pragma unroll
        for (int i = 0; i < 8; ++i) {
            int idx = base + i;
            if (idx < n) s += deg[idx];
        }
        red[t] = s;
        __syncthreads();
        #pragma unroll
        for (int off = 128; off >= 1; off >>= 1) {
            if (t < off) red[t] += red[t + off];
            __syncthreads();
        }
        if (t == 0) bsum[bid] = red[0];
    }
    gsync(ctl);

    // ---- P3: scan of block sums (block 0) ----
    if (bid == 0) {
        int* sh = (int*)smem;
        int orig = (t < nscan) ? bsum[t] : 0;
        sh[t] = orig;
        __syncthreads();
        for (int off = 1; off < 256; off <<= 1) {
            int add = (t >= off) ? sh[t - off] : 0;
            __syncthreads();
            sh[t] += add;
            __syncthreads();
        }
        if (t < nscan) bsum[t] = sh[t] - orig;
    }
    gsync(ctl);

    // ---- P4: final exclusive scan -> rowp, invd ----
    if (bid < nscan) {
        int* sh = (int*)smem;
        int base = bid * 2048 + t * 8;
        int loc[8];
        int s = 0;
        #pragma unroll
        for (int i = 0; i < 8; ++i) {
            int idx = base + i;
            int d = (idx < n) ? deg[idx] : 0;
            loc[i] = d;
            s += d;
        }
        sh[t] = s;
        __syncthreads();
        for (int off = 1; off < 256; off <<= 1) {
            int add = (t >= off) ? sh[t - off] : 0;
            __syncthreads();
            sh[t] += add;
            __syncthreads();
        }
        int run = bsum[bid] + (sh[t] - s);
        #pragma unroll
        for (int i = 0; i < 8; ++i) {
            int idx = base + i;
            if (idx < n) {
                rowp[idx] = run;
                int d = loc[i];
                run += d;
                invd[idx] = 1.0f / (float)(d > 1 ? d : 1);
            }
        }
        if (bid == 0 && t == 0) rowp[n] = E;
    }
    gsync(ctl);

    // ---- P5: scatter edge indices ----
    for (int e = gid; e < E; e += gstride) {
        int d = ds[e];
        int pos = rowp[d] + atomicAdd(&fill[d], 1);
        ei[pos] = e;
    }
    gsync(ctl);

    // ---- P6: deterministic order (insertion sort by edge id) + fill es/ep.
    // RK4 @ T=3 amplifies fp32 sum-order noise to O(1): determinism = correctness.
    for (int node = gid; node < n; node += gstride) {
        int b = rowp[node], e = rowp[node + 1];
        for (int i = b + 1; i < e; ++i) {
            int key = ei[i];
            int j = i - 1;
            while (j >= b && ei[j] > key) { ei[j + 1] = ei[j]; --j; }
            ei[j + 1] = key;
        }
        for (int i = b; i < e; ++i) {
            int id = ei[i];
            es[i] = sr[id];
            ep[i] = pE[id];
        }
    }
    gsync(ctl);

    // ---- P7: conv1 GEMM (work-stealing tiles) ----
    for (int tt; (tt = grab(&ctl[2], &tsh)) < ntiles; )
        conv1_tile(tt, n, x, Bc1, big0, big1, b1, As, Bs);
    gsync(ctl);

    // ---- P8: conv1 edge transform + tanh -> h ----
    for (int g = gid; g < n * 16; g += gstride) {
        int node = g >> 4;
        int c4 = (g & 15) << 2;
        int e = rowp[node], eend = rowp[node + 1];
        float ax = 0.f, ay = 0.f, az = 0.f, aw = 0.f;
        for (; e + 2 <= eend; e += 2) {
            int s0 = es[e], s1 = es[e + 1];
            float p0 = ep[e], p1 = ep[e + 1];
            float4 y0 = *reinterpret_cast<const float4*>(&big0[(size_t)s0 * 128 + c4]);
            float4 z0 = *reinterpret_cast<const float4*>(&big0[(size_t)s0 * 128 + 64 + c4]);
            float4 y1 = *reinterpret_cast<const float4*>(&big0[(size_t)s1 * 128 + c4]);
            float4 z1 = *reinterpret_cast<const float4*>(&big0[(size_t)s1 * 128 + 64 + c4]);
            ax += fmaf(p0, z0.x - y0.x, y0.x) + fmaf(p1, z1.x - y1.x, y1.x);
            ay += fmaf(p0, z0.y - y0.y, y0.y) + fmaf(p1, z1.y - y1.y, y1.y);
            az += fmaf(p0, z0.z - y0.z, y0.z) + fmaf(p1, z1.z - y1.z, y1.z);
            aw += fmaf(p0, z0.w - y0.w, y0.w) + fmaf(p1, z1.w - y1.w, y1.w);
        }
        for (; e < eend; ++e) {
            int s = es[e];
            float pe = ep[e];
            float4 y = *reinterpret_cast<const float4*>(&big0[(size_t)s * 128 + c4]);
            float4 z = *reinterpret_cast<const float4*>(&big0[(size_t)s * 128 + 64 + c4]);
            ax += fmaf(pe, z.x - y.x, y.x);
            ay += fmaf(pe, z.y - y.y, y.y);
            az += fmaf(pe, z.z - y.z, y.z);
            aw += fmaf(pe, z.w - y.w, y.w);
        }
        float w = invd[node];
        size_t idx = (size_t)node * 64 + c4;
        float4 b = *reinterpret_cast<const float4*>(&big1[idx]);
        float4 o = make_float4(tanhf(fmaf(ax, w, b.x)), tanhf(fmaf(ay, w, b.y)),
                               tanhf(fmaf(az, w, b.z)), tanhf(fmaf(aw, w, b.w)));
        *reinterpret_cast<float4*>(&h[idx]) = o;
    }
    gsync(ctl);

    // ---- RK4: 4 stages x (conv_a, conv_b) ----
    const float C1[4] = {1.5f, 1.5f, 3.f, 0.f};
    const float C2[4] = {0.f, 0.f, 0.f, 0.5f};
    const float C3[4] = {1.f, 2.f, 2.f, 1.f};
    for (int s = 0; s < 4; ++s) {
        const float* in0 = (s == 0) ? h : tb;
        for (int tt; (tt = grab(&ctl[3 + 2 * s], &tsh)) < ntiles; )
            hidden_tile(tt, n, in0, rowp, es, ep, invd, Bca, ba, big0, 0, u,
                        nullptr, nullptr, nullptr, nullptr, 0.f, 0.f, 0.f, As, Bs);
        gsync(ctl);
        for (int tt; (tt = grab(&ctl[4 + 2 * s], &tsh)) < ntiles; )
            hidden_tile(tt, n, u, rowp, es, ep, invd, Bcb, bbv, big0, 1, nullptr,
                        h, (s == 0) ? nullptr : rk, rk, tb, C1[s], C2[s], C3[s], As, Bs);
        gsync(ctl);
    }

    // ---- conv2 GEMM ----
    for (int tt; (tt = grab(&ctl[11], &tsh)) < ntiles; )
        conv2_tile(tt, n, tb, Bc2, big0, big1, b2, As, Bs);
    gsync(ctl);

    // ---- conv2 edge transform + tanh + log_softmax -> out ----
    for (int g = gid; g < n * 16; g += gstride) {
        int node = g >> 4;
        int c = g & 15;
        int e = rowp[node], eend = rowp[node + 1];
        float a = 0.f;
        for (; e + 4 <= eend; e += 4) {
            int s0 = es[e], s1 = es[e + 1], s2 = es[e + 2], s3 = es[e + 3];
            float p0 = ep[e], p1 = ep[e + 1], p2 = ep[e + 2], p3 = ep[e + 3];
            float y0 = big0[(size_t)s0 * 32 + c], z0 = big0[(size_t)s0 * 32 + 16 + c];
            float y1 = big0[(size_t)s1 * 32 + c], z1 = big0[(size_t)s1 * 32 + 16 + c];
            float y2 = big0[(size_t)s2 * 32 + c], z2 = big0[(size_t)s2 * 32 + 16 + c];
            float y3 = big0[(size_t)s3 * 32 + c], z3 = big0[(size_t)s3 * 32 + 16 + c];
            a += fmaf(p0, z0 - y0, y0);
            a += fmaf(p1, z1 - y1, y1);
            a += fmaf(p2, z2 - y2, y2);
            a += fmaf(p3, z3 - y3, y3);
        }
        for (; e < eend; ++e) {
            int s = es[e]; float pe = ep[e];
            float y = big0[(size_t)s * 32 + c], z = big0[(size_t)s * 32 + 16 + c];
            a += fmaf(pe, z - y, y);
        }
        float o = tanhf(a * invd[node] + big1[(size_t)node * 16 + c]);
        float m = o;
        #pragma unroll
        for (int off = 8; off >= 1; off >>= 1) m = fmaxf(m, __shfl_xor(m, off, 16));
        float ex = expf(o - m);
        float sm = ex;
        #pragma unroll
        for (int off = 8; off >= 1; off >>= 1) sm += __shfl_xor(sm, off, 16);
        out[(size_t)node * 16 + c] = (o - m) - logf(sm);
    }
}

// ---------------------------------------------------------------------------
// Host launcher: one memset + one persistent kernel.
// ---------------------------------------------------------------------------
extern "C" void kernel_launch(void* const* d_in, const int* in_sizes, int n_in,
                              void* d_out, int out_size, void* d_ws, size_t ws_size,
                              hipStream_t stream) {
    const float* x  = (const float*)d_in[0];
    const float* pE = (const float*)d_in[1];
    const int*   sr = (const int*)d_in[2];
    const int*   ds = (const int*)d_in[3];
    const float* W1 = (const float*)d_in[4];
    const float* R1 = (const float*)d_in[5];
    const float* b1 = (const float*)d_in[6];
    const float* Wa = (const float*)d_in[7];
    const float* Ra = (const float*)d_in[8];
    const float* ba = (const float*)d_in[9];
    const float* Wb = (const float*)d_in[10];
    const float* Rb = (const float*)d_in[11];
    const float* bb = (const float*)d_in[12];
    const float* W2 = (const float*)d_in[13];
    const float* R2 = (const float*)d_in[14];
    const float* b2 = (const float*)d_in[15];
    const int n = in_sizes[0] / 256;
    const int E = in_sizes[2];
    float* out = (float*)d_out;

    char* w = (char*)d_ws;
    auto alloc = [&](size_t bytes) -> void* {
        void* ptr = (void*)w;
        w += (bytes + 255) & ~(size_t)255;
        return ptr;
    };
    int*   ctl  = (int*)alloc(64);                    // [0]=cnt [1]=gen [2..11]=tile ctrs
    int*   deg  = (int*)alloc((size_t)n * 4);
    int*   fill = (int*)alloc((size_t)n * 4);
    int*   rowp = (int*)alloc((size_t)(n + 1) * 4);
    float* invd = (float*)alloc((size_t)n * 4);
    int*   bsum = (int*)alloc((size_t)256 * 4);
    int*   ei   = (int*)alloc((size_t)E * 4);
    int*   es   = (int*)alloc((size_t)E * 4);
    float* ep   = (float*)alloc((size_t)E * 4);
    float* Bc1  = (float*)alloc((size_t)256 * 192 * 4);
    float* Bca  = (float*)alloc((size_t)192 * 64 * 4);
    float* Bcb  = (float*)alloc((size_t)192 * 64 * 4);
    float* Bc2  = (float*)alloc((size_t)64 * 48 * 4);
    float* big0 = (float*)alloc((size_t)n * 128 * 4);  // yz / agg scratch / yz2
    float* big1 = (float*)alloc((size_t)n * 64 * 4);   // base / base2
    float* h    = (float*)alloc((size_t)n * 64 * 4);
    float* u    = (float*)alloc((size_t)n * 64 * 4);
    float* tb   = (float*)alloc((size_t)n * 64 * 4);
    float* rk   = (float*)alloc((size_t)n * 64 * 4);

    hipMemsetAsync(ctl, 0, 64, stream);
    mega<<<NBLK, NTHR, 0, stream>>>(x, pE, sr, ds, W1, R1, b1, Wa, Ra, ba,
                                    Wb, Rb, bb, W2, R2, b2, n, E,
                                    ctl, deg, fill, rowp, invd, bsum, ei, es, ep,
                                    Bc1, Bca, Bcb, Bc2,
                                    big0, big1, h, u, tb, rk, out);
}

// Round 7
// 933.063 us; speedup vs baseline: 8.2452x; 8.2452x over previous
//
#include <hip/hip_runtime.h>
#include <math.h>

static inline int ceil_div(int a, int b) { return (a + b - 1) / b; }

// ---------------------------------------------------------------------------
// Setup kernels (unchanged from round 5)
// ---------------------------------------------------------------------------

__global__ __launch_bounds__(256) void zero2(int* __restrict__ a, int* __restrict__ b,
                                             int n) {
    int i = blockIdx.x * 256 + threadIdx.x;
    if (i < n) { a[i] = 0; b[i] = 0; }
}

__global__ __launch_bounds__(256) void hist_kernel(const int* __restrict__ dst,
                                                   int* __restrict__ deg, int E) {
    int e = blockIdx.x * 256 + threadIdx.x;
    if (e < E) atomicAdd(&deg[dst[e]], 1);
}

__global__ __launch_bounds__(256) void scan_blocksum(const int* __restrict__ deg,
                                                     int* __restrict__ bsum, int n) {
    __shared__ int red[256];
    int t = threadIdx.x;
    int base = blockIdx.x * 2048 + t * 8;
    int s = 0;
    #pragma unroll
    for (int i = 0; i < 8; ++i) {
        int idx = base + i;
        if (idx < n) s += deg[idx];
    }
    red[t] = s;
    __syncthreads();
    #pragma unroll
    for (int off = 128; off >= 1; off >>= 1) {
        if (t < off) red[t] += red[t + off];
        __syncthreads();
    }
    if (t == 0) bsum[blockIdx.x] = red[0];
}

__global__ __launch_bounds__(256) void scan_tops(int* __restrict__ bsum, int nb) {
    __shared__ int sh[256];
    int t = threadIdx.x;
    int orig = (t < nb) ? bsum[t] : 0;
    sh[t] = orig;
    __syncthreads();
    for (int off = 1; off < 256; off <<= 1) {
        int add = (t >= off) ? sh[t - off] : 0;
        __syncthreads();
        sh[t] += add;
        __syncthreads();
    }
    if (t < nb) bsum[t] = sh[t] - orig;  // exclusive prefix
}

__global__ __launch_bounds__(256) void scan_final(const int* __restrict__ deg,
                                                  const int* __restrict__ bsum,
                                                  int* __restrict__ rowp,
                                                  float* __restrict__ invd,
                                                  int n, int E) {
    __shared__ int sh[256];
    int t = threadIdx.x;
    int base = blockIdx.x * 2048 + t * 8;
    int loc[8];
    int s = 0;
    #pragma unroll
    for (int i = 0; i < 8; ++i) {
        int idx = base + i;
        int d = (idx < n) ? deg[idx] : 0;
        loc[i] = d;
        s += d;
    }
    sh[t] = s;
    __syncthreads();
    for (int off = 1; off < 256; off <<= 1) {
        int add = (t >= off) ? sh[t - off] : 0;
        __syncthreads();
        sh[t] += add;
        __syncthreads();
    }
    int run = bsum[blockIdx.x] + (sh[t] - s);
    #pragma unroll
    for (int i = 0; i < 8; ++i) {
        int idx = base + i;
        if (idx < n) {
            rowp[idx] = run;
            int d = loc[i];
            run += d;
            invd[idx] = 1.0f / (float)(d > 1 ? d : 1);
        }
    }
    if (blockIdx.x == 0 && t == 0) rowp[n] = E;
}

__global__ __launch_bounds__(256) void scatter_idx(const int* __restrict__ dst,
                                                   const int* __restrict__ rowp,
                                                   int* __restrict__ fill,
                                                   int* __restrict__ ei, int E) {
    int e = blockIdx.x * 256 + threadIdx.x;
    if (e >= E) return;
    int d = dst[e];
    int pos = rowp[d] + atomicAdd(&fill[d], 1);
    ei[pos] = e;
}

// Deterministic intra-node edge order (matches segment_sum's edge-index order).
// RK4 @ T=3 amplifies fp32 sum-order noise to O(1): determinism & order =
// correctness, not hygiene. NEVER change accumulation grouping downstream.
__global__ __launch_bounds__(256) void sort_fill(const int* __restrict__ rowp,
                                                 int* __restrict__ ei,
                                                 const int* __restrict__ src,
                                                 const float* __restrict__ p,
                                                 int* __restrict__ es,
                                                 float* __restrict__ ep, int n) {
    int node = blockIdx.x * 256 + threadIdx.x;
    if (node >= n) return;
    int b = rowp[node], e = rowp[node + 1];
    for (int i = b + 1; i < e; ++i) {
        int key = ei[i];
        int j = i - 1;
        while (j >= b && ei[j] > key) { ei[j + 1] = ei[j]; --j; }
        ei[j + 1] = key;
    }
    for (int i = b; i < e; ++i) {
        int id = ei[i];
        es[i] = src[id];
        ep[i] = p[id];
    }
}

__global__ __launch_bounds__(256) void pack_all(
    const float* __restrict__ W1, const float* __restrict__ R1,
    const float* __restrict__ Wa, const float* __restrict__ Ra,
    const float* __restrict__ Wb, const float* __restrict__ Rb,
    const float* __restrict__ W2, const float* __restrict__ R2,
    float* __restrict__ Bc1, float* __restrict__ Bca,
    float* __restrict__ Bcb, float* __restrict__ Bc2) {
    int idx = blockIdx.x * 256 + threadIdx.x;
    const int S1 = 256 * 192, S2 = 192 * 64, S4 = 64 * 48;
    if (idx < S1) {
        int k = idx / 192, c = idx % 192;
        float v;
        if (c < 64)       v = W1[k * 64 + c];
        else if (c < 128) v = W1[256 * 64 + k * 64 + (c - 64)];
        else              v = R1[k * 64 + (c - 128)];
        Bc1[idx] = v;
        return;
    }
    idx -= S1;
    if (idx < S2) { Bca[idx] = (idx < 8192) ? Wa[idx] : Ra[idx - 8192]; return; }
    idx -= S2;
    if (idx < S2) { Bcb[idx] = (idx < 8192) ? Wb[idx] : Rb[idx - 8192]; return; }
    idx -= S2;
    if (idx < S4) {
        int k = idx / 48, c = idx % 48;
        float v;
        if (c < 16)      v = W2[k * 16 + c];
        else if (c < 32) v = W2[64 * 16 + k * 16 + (c - 16)];
        else             v = R2[k * 16 + (c - 32)];
        Bc2[idx] = v;
    }
}

// ---------------------------------------------------------------------------
// Edge aggregation (hidden convs), 8 lanes/node x 8 channels (2 dwordx4/edge):
// doubles outstanding loads per lane vs the 16-lane variant. Per-channel
// accumulation chain is IDENTICAL to previous rounds (4-edge unroll, same
// grouping) -> bitwise-identical results.
// ---------------------------------------------------------------------------
__global__ __launch_bounds__(256) void edge_agg64_v8(const float* __restrict__ x,
                                                     const int* __restrict__ rowp,
                                                     const int* __restrict__ es,
                                                     const float* __restrict__ ep,
                                                     const float* __restrict__ invd,
                                                     float* __restrict__ agg, int n) {
    int gid = blockIdx.x * 256 + threadIdx.x;
    int node = gid >> 3;
    if (node >= n) return;
    int c8 = (gid & 7) << 3;
    int e = rowp[node], eend = rowp[node + 1];
    float s[8] = {0.f, 0.f, 0.f, 0.f, 0.f, 0.f, 0.f, 0.f};
    float p[8] = {0.f, 0.f, 0.f, 0.f, 0.f, 0.f, 0.f, 0.f};
    for (; e + 4 <= eend; e += 4) {
        int n0 = es[e], n1 = es[e + 1], n2 = es[e + 2], n3 = es[e + 3];
        float p0 = ep[e], p1 = ep[e + 1], p2 = ep[e + 2], p3 = ep[e + 3];
        float4 v0a = *reinterpret_cast<const float4*>(&x[(size_t)n0 * 64 + c8]);
        float4 v0b = *reinterpret_cast<const float4*>(&x[(size_t)n0 * 64 + c8 + 4]);
        float4 v1a = *reinterpret_cast<const float4*>(&x[(size_t)n1 * 64 + c8]);
        float4 v1b = *reinterpret_cast<const float4*>(&x[(size_t)n1 * 64 + c8 + 4]);
        float4 v2a = *reinterpret_cast<const float4*>(&x[(size_t)n2 * 64 + c8]);
        float4 v2b = *reinterpret_cast<const float4*>(&x[(size_t)n2 * 64 + c8 + 4]);
        float4 v3a = *reinterpret_cast<const float4*>(&x[(size_t)n3 * 64 + c8]);
        float4 v3b = *reinterpret_cast<const float4*>(&x[(size_t)n3 * 64 + c8 + 4]);
        const float* f0 = &v0a.x; const float* f1 = &v1a.x;
        const float* f2 = &v2a.x; const float* f3 = &v3a.x;
        const float* g0 = &v0b.x; const float* g1 = &v1b.x;
        const float* g2 = &v2b.x; const float* g3 = &v3b.x;
        #pragma unroll
        for (int j = 0; j < 4; ++j) {
            s[j] += (f0[j] + f1[j]) + (f2[j] + f3[j]);
            p[j] = fmaf(p0, f0[j], fmaf(p1, f1[j], fmaf(p2, f2[j], fmaf(p3, f3[j], p[j]))));
        }
        #pragma unroll
        for (int j = 0; j < 4; ++j) {
            s[4 + j] += (g0[j] + g1[j]) + (g2[j] + g3[j]);
            p[4 + j] = fmaf(p0, g0[j], fmaf(p1, g1[j], fmaf(p2, g2[j], fmaf(p3, g3[j], p[4 + j]))));
        }
    }
    for (; e < eend; ++e) {
        int sn = es[e];
        float pe = ep[e];
        float4 va = *reinterpret_cast<const float4*>(&x[(size_t)sn * 64 + c8]);
        float4 vb = *reinterpret_cast<const float4*>(&x[(size_t)sn * 64 + c8 + 4]);
        const float* fa = &va.x; const float* fb = &vb.x;
        #pragma unroll
        for (int j = 0; j < 4; ++j) {
            s[j] += fa[j];        p[j] = fmaf(pe, fa[j], p[j]);
            s[4 + j] += fb[j];    p[4 + j] = fmaf(pe, fb[j], p[4 + j]);
        }
    }
    float w = invd[node];
    float4 a0, a1, b0, b1v;
    a0.x = (s[0] - p[0]) * w; a0.y = (s[1] - p[1]) * w;
    a0.z = (s[2] - p[2]) * w; a0.w = (s[3] - p[3]) * w;
    a1.x = (s[4] - p[4]) * w; a1.y = (s[5] - p[5]) * w;
    a1.z = (s[6] - p[6]) * w; a1.w = (s[7] - p[7]) * w;
    b0.x = p[0] * w; b0.y = p[1] * w; b0.z = p[2] * w; b0.w = p[3] * w;
    b1v.x = p[4] * w; b1v.y = p[5] * w; b1v.z = p[6] * w; b1v.w = p[7] * w;
    *reinterpret_cast<float4*>(&agg[(size_t)node * 128 + c8])          = a0;
    *reinterpret_cast<float4*>(&agg[(size_t)node * 128 + c8 + 4])      = a1;
    *reinterpret_cast<float4*>(&agg[(size_t)node * 128 + 64 + c8])     = b0;
    *reinterpret_cast<float4*>(&agg[(size_t)node * 128 + 64 + c8 + 4]) = b1v;
}

// ---------------------------------------------------------------------------
// Hidden GEMM, 32-row tiles (2x grid vs 64-row -> ~6 blocks/CU, grid-limit
// fix; round-5 showed register prefetch is the wrong tool). Micro 2x4.
// Same k-order per output element -> bitwise identical.
// ---------------------------------------------------------------------------
__global__ __launch_bounds__(256) void hidden_gemm32(
    const float* __restrict__ agg, const float* __restrict__ in,
    const float* __restrict__ B, const float* __restrict__ bias,
    int n, int mode, float* __restrict__ u_out,
    const float* __restrict__ hbuf, const float* __restrict__ acc_in,
    float* __restrict__ acc_out, float* __restrict__ t_out,
    float c1, float c2, float c3) {
    __shared__ __align__(16) float As[16][36];
    __shared__ __align__(16) float Bs[16][68];
    const int t = threadIdx.x;
    const int row0 = blockIdx.x * 32;
    const int ty = t >> 4, tx = t & 15;
    const int lrow = t >> 2, lk = (t & 3) << 2;   // threads 0..127 load A
    const int bkk = t >> 4, bcol = (t & 15) << 2;
    float acc[2][4];
    #pragma unroll
    for (int i = 0; i < 2; ++i)
        #pragma unroll
        for (int j = 0; j < 4; ++j) acc[i][j] = 0.f;

    for (int kt = 0; kt < 12; ++kt) {
        int k0 = kt << 4;
        if (t < 128) {
            int r = row0 + lrow;
            int kk = k0 + lk;
            float4 av = make_float4(0.f, 0.f, 0.f, 0.f);
            if (r < n)
                av = (kk < 128)
                    ? *reinterpret_cast<const float4*>(&agg[(size_t)r * 128 + kk])
                    : *reinterpret_cast<const float4*>(&in[(size_t)r * 64 + (kk - 128)]);
            As[lk + 0][lrow] = av.x; As[lk + 1][lrow] = av.y;
            As[lk + 2][lrow] = av.z; As[lk + 3][lrow] = av.w;
        }
        float4 bv = *reinterpret_cast<const float4*>(&B[(size_t)(k0 + bkk) * 64 + bcol]);
        *reinterpret_cast<float4*>(&Bs[bkk][bcol]) = bv;
        __syncthreads();
        #pragma unroll
        for (int kk = 0; kk < 16; ++kk) {
            float a0 = As[kk][ty * 2], a1 = As[kk][ty * 2 + 1];
            float4 b4 = *reinterpret_cast<const float4*>(&Bs[kk][tx << 2]);
            float bb[4] = {b4.x, b4.y, b4.z, b4.w};
            #pragma unroll
            for (int j = 0; j < 4; ++j) {
                acc[0][j] = fmaf(a0, bb[j], acc[0][j]);
                acc[1][j] = fmaf(a1, bb[j], acc[1][j]);
            }
        }
        __syncthreads();
    }

    float4 bia = *reinterpret_cast<const float4*>(&bias[tx << 2]);
    #pragma unroll
    for (int i = 0; i < 2; ++i) {
        int r = row0 + ty * 2 + i;
        if (r >= n) continue;
        size_t idx = (size_t)r * 64 + (tx << 2);
        float4 v = make_float4(acc[i][0] + bia.x, acc[i][1] + bia.y,
                               acc[i][2] + bia.z, acc[i][3] + bia.w);
        if (mode == 0) {
            *reinterpret_cast<float4*>(&u_out[idx]) = v;
        } else {
            float4 ai = make_float4(0.f, 0.f, 0.f, 0.f);
            if (acc_in) ai = *reinterpret_cast<const float4*>(&acc_in[idx]);
            float4 an = make_float4(ai.x + c3 * v.x, ai.y + c3 * v.y,
                                    ai.z + c3 * v.z, ai.w + c3 * v.w);
            *reinterpret_cast<float4*>(&acc_out[idx]) = an;
            float4 hb = *reinterpret_cast<const float4*>(&hbuf[idx]);
            float4 to = make_float4(hb.x + c1 * v.x + c2 * an.x,
                                    hb.y + c1 * v.y + c2 * an.y,
                                    hb.z + c1 * v.z + c2 * an.z,
                                    hb.w + c1 * v.w + c2 * an.w);
            *reinterpret_cast<float4*>(&t_out[idx]) = to;
        }
    }
}

// ---------------------------------------------------------------------------
// conv1 GEMM, 32-row tiles, micro 2x12, single column strip.
// ---------------------------------------------------------------------------
__global__ __launch_bounds__(256) void conv1_gemm32(const float* __restrict__ x,
                                                    const float* __restrict__ B,
                                                    int n, float* __restrict__ yz,
                                                    float* __restrict__ base,
                                                    const float* __restrict__ b1) {
    __shared__ __align__(16) float As[16][36];
    __shared__ __align__(16) float Bs[16][200];
    const int t = threadIdx.x;
    const int row0 = blockIdx.x * 32;
    const int ty = t >> 4, tx = t & 15;
    const int lrow = t >> 2, lk = (t & 3) << 2;
    const int bkk = t >> 4, bcol = (t & 15) << 2;
    float acc[2][12];
    #pragma unroll
    for (int i = 0; i < 2; ++i)
        #pragma unroll
        for (int j = 0; j < 12; ++j) acc[i][j] = 0.f;

    for (int kt = 0; kt < 16; ++kt) {
        int k0 = kt << 4;
        if (t < 128) {
            int r = row0 + lrow;
            float4 av = make_float4(0.f, 0.f, 0.f, 0.f);
            if (r < n)
                av = *reinterpret_cast<const float4*>(&x[(size_t)r * 256 + k0 + lk]);
            As[lk + 0][lrow] = av.x; As[lk + 1][lrow] = av.y;
            As[lk + 2][lrow] = av.z; As[lk + 3][lrow] = av.w;
        }
        const float* bp = &B[(size_t)(k0 + bkk) * 192 + bcol];
        float4 bv0 = *reinterpret_cast<const float4*>(bp);
        float4 bv1 = *reinterpret_cast<const float4*>(bp + 64);
        float4 bv2 = *reinterpret_cast<const float4*>(bp + 128);
        *reinterpret_cast<float4*>(&Bs[bkk][bcol])       = bv0;
        *reinterpret_cast<float4*>(&Bs[bkk][bcol + 64])  = bv1;
        *reinterpret_cast<float4*>(&Bs[bkk][bcol + 128]) = bv2;
        __syncthreads();
        #pragma unroll
        for (int kk = 0; kk < 16; ++kk) {
            float a0 = As[kk][ty * 2], a1 = As[kk][ty * 2 + 1];
            float4 b0 = *reinterpret_cast<const float4*>(&Bs[kk][tx << 2]);
            float4 b1q = *reinterpret_cast<const float4*>(&Bs[kk][(tx << 2) + 64]);
            float4 b2q = *reinterpret_cast<const float4*>(&Bs[kk][(tx << 2) + 128]);
            float bb[12] = {b0.x, b0.y, b0.z, b0.w, b1q.x, b1q.y, b1q.z, b1q.w,
                            b2q.x, b2q.y, b2q.z, b2q.w};
            #pragma unroll
            for (int j = 0; j < 12; ++j) {
                acc[0][j] = fmaf(a0, bb[j], acc[0][j]);
                acc[1][j] = fmaf(a1, bb[j], acc[1][j]);
            }
        }
        __syncthreads();
    }

    float4 bb4 = *reinterpret_cast<const float4*>(&b1[tx << 2]);
    #pragma unroll
    for (int i = 0; i < 2; ++i) {
        int r = row0 + ty * 2 + i;
        if (r >= n) continue;
        float4 q0 = make_float4(acc[i][0], acc[i][1], acc[i][2], acc[i][3]);
        float4 q1 = make_float4(acc[i][4], acc[i][5], acc[i][6], acc[i][7]);
        float4 q2 = make_float4(acc[i][8] + bb4.x, acc[i][9] + bb4.y,
                                acc[i][10] + bb4.z, acc[i][11] + bb4.w);
        *reinterpret_cast<float4*>(&yz[(size_t)r * 128 + (tx << 2)]) = q0;
        *reinterpret_cast<float4*>(&yz[(size_t)r * 128 + 64 + (tx << 2)]) = q1;
        *reinterpret_cast<float4*>(&base[(size_t)r * 64 + (tx << 2)]) = q2;
    }
}

// ---------------------------------------------------------------------------
// conv1 edge transform (8 lanes/node x 8 ch; per-channel order identical to
// the 16-lane 2-unroll version).
// ---------------------------------------------------------------------------
__global__ __launch_bounds__(256) void edge_tf64_v8(const float* __restrict__ yz,
                                                    const int* __restrict__ rowp,
                                                    const int* __restrict__ es,
                                                    const float* __restrict__ ep,
                                                    const float* __restrict__ invd,
                                                    const float* __restrict__ base,
                                                    float* __restrict__ out, int n) {
    int gid = blockIdx.x * 256 + threadIdx.x;
    int node = gid >> 3;
    if (node >= n) return;
    int c8 = (gid & 7) << 3;
    int e = rowp[node], eend = rowp[node + 1];
    float a[8] = {0.f, 0.f, 0.f, 0.f, 0.f, 0.f, 0.f, 0.f};
    for (; e + 2 <= eend; e += 2) {
        int s0 = es[e], s1 = es[e + 1];
        float p0 = ep[e], p1 = ep[e + 1];
        float4 y0a = *reinterpret_cast<const float4*>(&yz[(size_t)s0 * 128 + c8]);
        float4 y0b = *reinterpret_cast<const float4*>(&yz[(size_t)s0 * 128 + c8 + 4]);
        float4 z0a = *reinterpret_cast<const float4*>(&yz[(size_t)s0 * 128 + 64 + c8]);
        float4 z0b = *reinterpret_cast<const float4*>(&yz[(size_t)s0 * 128 + 64 + c8 + 4]);
        float4 y1a = *reinterpret_cast<const float4*>(&yz[(size_t)s1 * 128 + c8]);
        float4 y1b = *reinterpret_cast<const float4*>(&yz[(size_t)s1 * 128 + c8 + 4]);
        float4 z1a = *reinterpret_cast<const float4*>(&yz[(size_t)s1 * 128 + 64 + c8]);
        float4 z1b = *reinterpret_cast<const float4*>(&yz[(size_t)s1 * 128 + 64 + c8 + 4]);
        const float* ya0 = &y0a.x; const float* yb0 = &y0b.x;
        const float* za0 = &z0a.x; const float* zb0 = &z0b.x;
        const float* ya1 = &y1a.x; const float* yb1 = &y1b.x;
        const float* za1 = &z1a.x; const float* zb1 = &z1b.x;
        #pragma unroll
        for (int j = 0; j < 4; ++j) {
            a[j]     += fmaf(p0, za0[j] - ya0[j], ya0[j]) + fmaf(p1, za1[j] - ya1[j], ya1[j]);
            a[4 + j] += fmaf(p0, zb0[j] - yb0[j], yb0[j]) + fmaf(p1, zb1[j] - yb1[j], yb1[j]);
        }
    }
    for (; e < eend; ++e) {
        int s = es[e];
        float pe = ep[e];
        float4 ya = *reinterpret_cast<const float4*>(&yz[(size_t)s * 128 + c8]);
        float4 yb = *reinterpret_cast<const float4*>(&yz[(size_t)s * 128 + c8 + 4]);
        float4 za = *reinterpret_cast<const float4*>(&yz[(size_t)s * 128 + 64 + c8]);
        float4 zb = *reinterpret_cast<const float4*>(&yz[(size_t)s * 128 + 64 + c8 + 4]);
        const float* fy = &ya.x; const float* gy = &yb.x;
        const float* fz = &za.x; const float* gz = &zb.x;
        #pragma unroll
        for (int j = 0; j < 4; ++j) {
            a[j]     += fmaf(pe, fz[j] - fy[j], fy[j]);
            a[4 + j] += fmaf(pe, gz[j] - gy[j], gy[j]);
        }
    }
    float w = invd[node];
    size_t idx = (size_t)node * 64 + c8;
    float4 ba = *reinterpret_cast<const float4*>(&base[idx]);
    float4 bbv = *reinterpret_cast<const float4*>(&base[idx + 4]);
    float4 o0 = make_float4(tanhf(fmaf(a[0], w, ba.x)), tanhf(fmaf(a[1], w, ba.y)),
                            tanhf(fmaf(a[2], w, ba.z)), tanhf(fmaf(a[3], w, ba.w)));
    float4 o1 = make_float4(tanhf(fmaf(a[4], w, bbv.x)), tanhf(fmaf(a[5], w, bbv.y)),
                            tanhf(fmaf(a[6], w, bbv.z)), tanhf(fmaf(a[7], w, bbv.w)));
    *reinterpret_cast<float4*>(&out[idx]) = o0;
    *reinterpret_cast<float4*>(&out[idx + 4]) = o1;
}

__global__ __launch_bounds__(256) void edge_tf16_lsm(const float* __restrict__ yz,
                                                     const int* __restrict__ rowp,
                                                     const int* __restrict__ es,
                                                     const float* __restrict__ ep,
                                                     const float* __restrict__ invd,
                                                     const float* __restrict__ base,
                                                     float* __restrict__ out, int n) {
    int gid = blockIdx.x * 256 + threadIdx.x;
    int node = gid >> 4;
    if (node >= n) return;
    int c = gid & 15;
    int e = rowp[node], eend = rowp[node + 1];
    float a = 0.f;
    for (; e + 4 <= eend; e += 4) {
        int s0 = es[e], s1 = es[e + 1], s2 = es[e + 2], s3 = es[e + 3];
        float p0 = ep[e], p1 = ep[e + 1], p2 = ep[e + 2], p3 = ep[e + 3];
        float y0 = yz[(size_t)s0 * 32 + c],      z0 = yz[(size_t)s0 * 32 + 16 + c];
        float y1 = yz[(size_t)s1 * 32 + c],      z1 = yz[(size_t)s1 * 32 + 16 + c];
        float y2 = yz[(size_t)s2 * 32 + c],      z2 = yz[(size_t)s2 * 32 + 16 + c];
        float y3 = yz[(size_t)s3 * 32 + c],      z3 = yz[(size_t)s3 * 32 + 16 + c];
        a += fmaf(p0, z0 - y0, y0);
        a += fmaf(p1, z1 - y1, y1);
        a += fmaf(p2, z2 - y2, y2);
        a += fmaf(p3, z3 - y3, y3);
    }
    for (; e < eend; ++e) {
        int s = es[e]; float pe = ep[e];
        float y = yz[(size_t)s * 32 + c], z = yz[(size_t)s * 32 + 16 + c];
        a += fmaf(pe, z - y, y);
    }
    float o = tanhf(a * invd[node] + base[(size_t)node * 16 + c]);
    float m = o;
    #pragma unroll
    for (int off = 8; off >= 1; off >>= 1) m = fmaxf(m, __shfl_xor(m, off, 16));
    float ex = expf(o - m);
    float s = ex;
    #pragma unroll
    for (int off = 8; off >= 1; off >>= 1) s += __shfl_xor(s, off, 16);
    out[(size_t)node * 16 + c] = (o - m) - logf(s);
}

// ---------------------------------------------------------------------------
// conv2 GEMM (K=64, M=48), 64-row tiles (small kernel, fine as-is)
// ---------------------------------------------------------------------------
__global__ __launch_bounds__(256) void gemm_tiled(
    const float* __restrict__ A0, int lda0, int K0,
    const float* __restrict__ A1, int lda1,
    const float* __restrict__ B,
    int n, int K, int M,
    float* __restrict__ out0, int w0, const float* __restrict__ bias0,
    float* __restrict__ out1, int w1, const float* __restrict__ bias1,
    int split) {
    __shared__ __align__(16) float As[16][68];
    __shared__ __align__(16) float Bs[16][68];
    const int t = threadIdx.x;
    const int row0 = blockIdx.x * 64;
    const int col0 = blockIdx.y * 64;
    const int ty = t >> 4, tx = t & 15;
    const int lrow = t >> 2, lk = (t & 3) << 2;
    const int bkk = t >> 4, bcol = (t & 15) << 2;
    float acc[4][4];
    #pragma unroll
    for (int i = 0; i < 4; ++i)
        #pragma unroll
        for (int j = 0; j < 4; ++j) acc[i][j] = 0.f;

    for (int k0 = 0; k0 < K; k0 += 16) {
        float4 av = make_float4(0.f, 0.f, 0.f, 0.f);
        {
            int r = row0 + lrow;
            if (r < n) {
                int kk = k0 + lk;
                const float* src = (kk < K0)
                    ? (A0 + (size_t)r * lda0 + kk)
                    : (A1 + (size_t)r * lda1 + (kk - K0));
                av = *reinterpret_cast<const float4*>(src);
            }
        }
        float4 bv = make_float4(0.f, 0.f, 0.f, 0.f);
        {
            int c = col0 + bcol;
            int kk = k0 + bkk;
            if (c < M) bv = *reinterpret_cast<const float4*>(B + (size_t)kk * M + c);
        }
        As[lk + 0][lrow] = av.x; As[lk + 1][lrow] = av.y;
        As[lk + 2][lrow] = av.z; As[lk + 3][lrow] = av.w;
        *reinterpret_cast<float4*>(&Bs[bkk][bcol]) = bv;
        __syncthreads();
        #pragma unroll
        for (int kk = 0; kk < 16; ++kk) {
            float4 a4 = *reinterpret_cast<const float4*>(&As[kk][ty << 2]);
            float4 b4 = *reinterpret_cast<const float4*>(&Bs[kk][tx << 2]);
            float aa[4] = {a4.x, a4.y, a4.z, a4.w};
            float bb[4] = {b4.x, b4.y, b4.z, b4.w};
            #pragma unroll
            for (int i = 0; i < 4; ++i)
                #pragma unroll
                for (int j = 0; j < 4; ++j)
                    acc[i][j] = fmaf(aa[i], bb[j], acc[i][j]);
        }
        __syncthreads();
    }

    #pragma unroll
    for (int i = 0; i < 4; ++i) {
        int r = row0 + (ty << 2) + i;
        if (r >= n) continue;
        #pragma unroll
        for (int j = 0; j < 4; ++j) {
            int c = col0 + (tx << 2) + j;
            if (c >= M) continue;
            float v = acc[i][j];
            if (c < split) {
                if (bias0) v += bias0[c];
                out0[(size_t)r * w0 + c] = v;
            } else {
                int cc = c - split;
                if (bias1) v += bias1[cc];
                out1[(size_t)r * w1 + cc] = v;
            }
        }
    }
}

// ---------------------------------------------------------------------------
// Host-side launcher
// ---------------------------------------------------------------------------

static void hidden_conv(hipStream_t stream, const float* in, float* agg,
                        const int* rowp, const int* es, const float* ep,
                        const float* invd, const float* Bc, const float* bias, int n,
                        int mode, float* u_out,
                        const float* h, const float* acc_in, float* acc_out,
                        float* t_out, float c1, float c2, float c3) {
    edge_agg64_v8<<<ceil_div(n * 8, 256), 256, 0, stream>>>(in, rowp, es, ep, invd,
                                                            agg, n);
    hidden_gemm32<<<ceil_div(n, 32), 256, 0, stream>>>(agg, in, Bc, bias, n, mode,
                                                       u_out, h, acc_in, acc_out,
                                                       t_out, c1, c2, c3);
}

extern "C" void kernel_launch(void* const* d_in, const int* in_sizes, int n_in,
                              void* d_out, int out_size, void* d_ws, size_t ws_size,
                              hipStream_t stream) {
    const float* x  = (const float*)d_in[0];
    const float* pE = (const float*)d_in[1];
    const int*   sr = (const int*)d_in[2];
    const int*   ds = (const int*)d_in[3];
    const float* W1 = (const float*)d_in[4];
    const float* R1 = (const float*)d_in[5];
    const float* b1 = (const float*)d_in[6];
    const float* Wa = (const float*)d_in[7];
    const float* Ra = (const float*)d_in[8];
    const float* ba = (const float*)d_in[9];
    const float* Wb = (const float*)d_in[10];
    const float* Rb = (const float*)d_in[11];
    const float* bb = (const float*)d_in[12];
    const float* W2 = (const float*)d_in[13];
    const float* R2 = (const float*)d_in[14];
    const float* b2 = (const float*)d_in[15];
    const int n = in_sizes[0] / 256;
    const int E = in_sizes[2];
    float* out = (float*)d_out;

    char* w = (char*)d_ws;
    auto alloc = [&](size_t bytes) -> void* {
        void* ptr = (void*)w;
        w += (bytes + 255) & ~(size_t)255;
        return ptr;
    };
    int nscan = ceil_div(n, 2048);
    int*   deg  = (int*)alloc((size_t)n * 4);
    int*   fill = (int*)alloc((size_t)n * 4);
    int*   rowp = (int*)alloc((size_t)(n + 1) * 4);
    float* invd = (float*)alloc((size_t)n * 4);
    int*   bsum = (int*)alloc((size_t)256 * 4);
    int*   ei   = (int*)alloc((size_t)E * 4);
    int*   es   = (int*)alloc((size_t)E * 4);
    float* ep   = (float*)alloc((size_t)E * 4);
    float* Bc1  = (float*)alloc((size_t)256 * 192 * 4);
    float* Bca  = (float*)alloc((size_t)192 * 64 * 4);
    float* Bcb  = (float*)alloc((size_t)192 * 64 * 4);
    float* Bc2  = (float*)alloc((size_t)64 * 48 * 4);
    float* big0 = (float*)alloc((size_t)n * 128 * 4);  // yz / agg buffer
    float* big1 = (float*)alloc((size_t)n * 64 * 4);   // base buffer
    float* h    = (float*)alloc((size_t)n * 64 * 4);
    float* u    = (float*)alloc((size_t)n * 64 * 4);
    float* tb   = (float*)alloc((size_t)n * 64 * 4);
    float* acc  = (float*)alloc((size_t)n * 64 * 4);

    const int PACK_TOTAL = 256 * 192 + 2 * 192 * 64 + 64 * 48;

    zero2<<<ceil_div(n, 256), 256, 0, stream>>>(deg, fill, n);
    pack_all<<<ceil_div(PACK_TOTAL, 256), 256, 0, stream>>>(W1, R1, Wa, Ra, Wb, Rb,
                                                            W2, R2, Bc1, Bca, Bcb, Bc2);
    hist_kernel<<<ceil_div(E, 256), 256, 0, stream>>>(ds, deg, E);
    scan_blocksum<<<nscan, 256, 0, stream>>>(deg, bsum, n);
    scan_tops<<<1, 256, 0, stream>>>(bsum, nscan);
    scan_final<<<nscan, 256, 0, stream>>>(deg, bsum, rowp, invd, n, E);
    scatter_idx<<<ceil_div(E, 256), 256, 0, stream>>>(ds, rowp, fill, ei, E);
    sort_fill<<<ceil_div(n, 256), 256, 0, stream>>>(rowp, ei, sr, pE, es, ep, n);

    // conv1: x @ [W1_0|W1_1|R1] -> yz(big0), base(big1)+b1; then edge transform
    conv1_gemm32<<<ceil_div(n, 32), 256, 0, stream>>>(x, Bc1, n, big0, big1, b1);
    edge_tf64_v8<<<ceil_div(n * 8, 256), 256, 0, stream>>>(big0, rowp, es, ep, invd,
                                                           big1, h, n);

    // RK4 over f(y) = conv_b(conv_a(y)), T=3
    // k1
    hidden_conv(stream, h, big0, rowp, es, ep, invd, Bca, ba, n, 0, u,
                nullptr, nullptr, nullptr, nullptr, 0.f, 0.f, 0.f);
    hidden_conv(stream, u, big0, rowp, es, ep, invd, Bcb, bb, n, 1, nullptr,
                h, nullptr, acc, tb, 1.5f, 0.f, 1.f);
    // k2
    hidden_conv(stream, tb, big0, rowp, es, ep, invd, Bca, ba, n, 0, u,
                nullptr, nullptr, nullptr, nullptr, 0.f, 0.f, 0.f);
    hidden_conv(stream, u, big0, rowp, es, ep, invd, Bcb, bb, n, 1, nullptr,
                h, acc, acc, tb, 1.5f, 0.f, 2.f);
    // k3
    hidden_conv(stream, tb, big0, rowp, es, ep, invd, Bca, ba, n, 0, u,
                nullptr, nullptr, nullptr, nullptr, 0.f, 0.f, 0.f);
    hidden_conv(stream, u, big0, rowp, es, ep, invd, Bcb, bb, n, 1, nullptr,
                h, acc, acc, tb, 3.f, 0.f, 2.f);
    // k4: t_out becomes h_new = h + 0.5*(k1+2k2+2k3+k4)
    hidden_conv(stream, tb, big0, rowp, es, ep, invd, Bca, ba, n, 0, u,
                nullptr, nullptr, nullptr, nullptr, 0.f, 0.f, 0.f);
    hidden_conv(stream, u, big0, rowp, es, ep, invd, Bcb, bb, n, 1, nullptr,
                h, acc, acc, tb, 0.f, 0.5f, 1.f);

    // conv2: h_new @ [W2_0|W2_1|R2] -> yz2(big0,w=32), base2(big1,w=16)+b2
    gemm_tiled<<<dim3(ceil_div(n, 64), 1), 256, 0, stream>>>(
        tb, 64, 64, nullptr, 0, Bc2, n, 64, 48,
        big0, 32, nullptr, big1, 16, b2, 32);
    edge_tf16_lsm<<<ceil_div(n * 16, 256), 256, 0, stream>>>(big0, rowp, es, ep, invd,
                                                             big1, out, n);
}

// Round 8
// 878.900 us; speedup vs baseline: 8.7533x; 1.0616x over previous
//
#include <hip/hip_runtime.h>
#include <math.h>

static inline int ceil_div(int a, int b) { return (a + b - 1) / b; }

// ---------------------------------------------------------------------------
// Setup kernels
// ---------------------------------------------------------------------------

__global__ __launch_bounds__(256) void zero2(int* __restrict__ a, int* __restrict__ b,
                                             int n) {
    int i = blockIdx.x * 256 + threadIdx.x;
    if (i < n) { a[i] = 0; b[i] = 0; }
}

__global__ __launch_bounds__(256) void hist_kernel(const int* __restrict__ dst,
                                                   int* __restrict__ deg, int E) {
    int e = blockIdx.x * 256 + threadIdx.x;
    if (e < E) atomicAdd(&deg[dst[e]], 1);
}

__global__ __launch_bounds__(256) void scan_blocksum(const int* __restrict__ deg,
                                                     int* __restrict__ bsum, int n) {
    __shared__ int red[256];
    int t = threadIdx.x;
    int base = blockIdx.x * 2048 + t * 8;
    int s = 0;
    #pragma unroll
    for (int i = 0; i < 8; ++i) {
        int idx = base + i;
        if (idx < n) s += deg[idx];
    }
    red[t] = s;
    __syncthreads();
    #pragma unroll
    for (int off = 128; off >= 1; off >>= 1) {
        if (t < off) red[t] += red[t + off];
        __syncthreads();
    }
    if (t == 0) bsum[blockIdx.x] = red[0];
}

__global__ __launch_bounds__(256) void scan_tops(int* __restrict__ bsum, int nb) {
    __shared__ int sh[256];
    int t = threadIdx.x;
    int orig = (t < nb) ? bsum[t] : 0;
    sh[t] = orig;
    __syncthreads();
    for (int off = 1; off < 256; off <<= 1) {
        int add = (t >= off) ? sh[t - off] : 0;
        __syncthreads();
        sh[t] += add;
        __syncthreads();
    }
    if (t < nb) bsum[t] = sh[t] - orig;  // exclusive prefix
}

__global__ __launch_bounds__(256) void scan_final(const int* __restrict__ deg,
                                                  const int* __restrict__ bsum,
                                                  int* __restrict__ rowp,
                                                  float* __restrict__ invd,
                                                  int n, int E) {
    __shared__ int sh[256];
    int t = threadIdx.x;
    int base = blockIdx.x * 2048 + t * 8;
    int loc[8];
    int s = 0;
    #pragma unroll
    for (int i = 0; i < 8; ++i) {
        int idx = base + i;
        int d = (idx < n) ? deg[idx] : 0;
        loc[i] = d;
        s += d;
    }
    sh[t] = s;
    __syncthreads();
    for (int off = 1; off < 256; off <<= 1) {
        int add = (t >= off) ? sh[t - off] : 0;
        __syncthreads();
        sh[t] += add;
        __syncthreads();
    }
    int run = bsum[blockIdx.x] + (sh[t] - s);
    #pragma unroll
    for (int i = 0; i < 8; ++i) {
        int idx = base + i;
        if (idx < n) {
            rowp[idx] = run;
            int d = loc[i];
            run += d;
            invd[idx] = 1.0f / (float)(d > 1 ? d : 1);
        }
    }
    if (blockIdx.x == 0 && t == 0) rowp[n] = E;
}

__global__ __launch_bounds__(256) void scatter_idx(const int* __restrict__ dst,
                                                   const int* __restrict__ rowp,
                                                   int* __restrict__ fill,
                                                   int* __restrict__ ei, int E) {
    int e = blockIdx.x * 256 + threadIdx.x;
    if (e >= E) return;
    int d = dst[e];
    int pos = rowp[d] + atomicAdd(&fill[d], 1);
    ei[pos] = e;
}

// Deterministic intra-node edge order (matches segment_sum's edge-index order).
// RK4 @ T=3 amplifies fp32 sum-order noise to O(1): determinism & order =
// correctness. NEVER change accumulation grouping downstream.
__global__ __launch_bounds__(256) void sort_fill(const int* __restrict__ rowp,
                                                 int* __restrict__ ei,
                                                 const int* __restrict__ src,
                                                 const float* __restrict__ p,
                                                 int* __restrict__ es,
                                                 float* __restrict__ ep, int n) {
    int node = blockIdx.x * 256 + threadIdx.x;
    if (node >= n) return;
    int b = rowp[node], e = rowp[node + 1];
    for (int i = b + 1; i < e; ++i) {
        int key = ei[i];
        int j = i - 1;
        while (j >= b && ei[j] > key) { ei[j + 1] = ei[j]; --j; }
        ei[j + 1] = key;
    }
    for (int i = b; i < e; ++i) {
        int id = ei[i];
        es[i] = src[id];
        ep[i] = p[id];
    }
}

__global__ __launch_bounds__(256) void pack_all(
    const float* __restrict__ W1, const float* __restrict__ R1,
    const float* __restrict__ Wa, const float* __restrict__ Ra,
    const float* __restrict__ Wb, const float* __restrict__ Rb,
    const float* __restrict__ W2, const float* __restrict__ R2,
    float* __restrict__ Bc1, float* __restrict__ Bca,
    float* __restrict__ Bcb, float* __restrict__ Bc2) {
    int idx = blockIdx.x * 256 + threadIdx.x;
    const int S1 = 256 * 192, S2 = 192 * 64, S4 = 64 * 48;
    if (idx < S1) {
        int k = idx / 192, c = idx % 192;
        float v;
        if (c < 64)       v = W1[k * 64 + c];
        else if (c < 128) v = W1[256 * 64 + k * 64 + (c - 64)];
        else              v = R1[k * 64 + (c - 128)];
        Bc1[idx] = v;
        return;
    }
    idx -= S1;
    if (idx < S2) { Bca[idx] = (idx < 8192) ? Wa[idx] : Ra[idx - 8192]; return; }
    idx -= S2;
    if (idx < S2) { Bcb[idx] = (idx < 8192) ? Wb[idx] : Rb[idx - 8192]; return; }
    idx -= S2;
    if (idx < S4) {
        int k = idx / 48, c = idx % 48;
        float v;
        if (c < 16)      v = W2[k * 16 + c];
        else if (c < 32) v = W2[64 * 16 + k * 16 + (c - 16)];
        else             v = R2[k * 16 + (c - 32)];
        Bc2[idx] = v;
    }
}

// ---------------------------------------------------------------------------
// Edge aggregation (hidden convs): 16 lanes/node x float4 (r5's best variant).
// ---------------------------------------------------------------------------
__global__ __launch_bounds__(256) void edge_agg64_v4(const float* __restrict__ x,
                                                     const int* __restrict__ rowp,
                                                     const int* __restrict__ es,
                                                     const float* __restrict__ ep,
                                                     const float* __restrict__ invd,
                                                     float* __restrict__ agg, int n) {
    int gid = blockIdx.x * 256 + threadIdx.x;
    int node = gid >> 4;
    if (node >= n) return;
    int c4 = (gid & 15) << 2;
    int e = rowp[node], eend = rowp[node + 1];
    float sx = 0.f, sy = 0.f, sz = 0.f, sw = 0.f;
    float px = 0.f, py = 0.f, pz = 0.f, pw = 0.f;
    for (; e + 4 <= eend; e += 4) {
        int s0 = es[e], s1 = es[e + 1], s2 = es[e + 2], s3 = es[e + 3];
        float p0 = ep[e], p1 = ep[e + 1], p2 = ep[e + 2], p3 = ep[e + 3];
        float4 v0 = *reinterpret_cast<const float4*>(&x[(size_t)s0 * 64 + c4]);
        float4 v1 = *reinterpret_cast<const float4*>(&x[(size_t)s1 * 64 + c4]);
        float4 v2 = *reinterpret_cast<const float4*>(&x[(size_t)s2 * 64 + c4]);
        float4 v3 = *reinterpret_cast<const float4*>(&x[(size_t)s3 * 64 + c4]);
        sx += (v0.x + v1.x) + (v2.x + v3.x);
        sy += (v0.y + v1.y) + (v2.y + v3.y);
        sz += (v0.z + v1.z) + (v2.z + v3.z);
        sw += (v0.w + v1.w) + (v2.w + v3.w);
        px = fmaf(p0, v0.x, fmaf(p1, v1.x, fmaf(p2, v2.x, fmaf(p3, v3.x, px))));
        py = fmaf(p0, v0.y, fmaf(p1, v1.y, fmaf(p2, v2.y, fmaf(p3, v3.y, py))));
        pz = fmaf(p0, v0.z, fmaf(p1, v1.z, fmaf(p2, v2.z, fmaf(p3, v3.z, pz))));
        pw = fmaf(p0, v0.w, fmaf(p1, v1.w, fmaf(p2, v2.w, fmaf(p3, v3.w, pw))));
    }
    for (; e < eend; ++e) {
        int s = es[e];
        float pe = ep[e];
        float4 v = *reinterpret_cast<const float4*>(&x[(size_t)s * 64 + c4]);
        sx += v.x; sy += v.y; sz += v.z; sw += v.w;
        px = fmaf(pe, v.x, px); py = fmaf(pe, v.y, py);
        pz = fmaf(pe, v.z, pz); pw = fmaf(pe, v.w, pw);
    }
    float w = invd[node];
    float4 a0 = make_float4((sx - px) * w, (sy - py) * w, (sz - pz) * w, (sw - pw) * w);
    float4 a1 = make_float4(px * w, py * w, pz * w, pw * w);
    *reinterpret_cast<float4*>(&agg[(size_t)node * 128 + c4]) = a0;
    *reinterpret_cast<float4*>(&agg[(size_t)node * 128 + 64 + c4]) = a1;
}

// ---------------------------------------------------------------------------
// Hidden GEMM, double-buffered 64-row tiles (r5's best variant).
// ---------------------------------------------------------------------------
__global__ __launch_bounds__(256) void hidden_gemm_db(
    const float* __restrict__ agg, const float* __restrict__ in,
    const float* __restrict__ B, const float* __restrict__ bias,
    int n, int mode, float* __restrict__ u_out,
    const float* __restrict__ hbuf, const float* __restrict__ acc_in,
    float* __restrict__ acc_out, float* __restrict__ t_out,
    float c1, float c2, float c3) {
    __shared__ __align__(16) float As[2][16][68];
    __shared__ __align__(16) float Bs[2][16][68];
    const int t = threadIdx.x;
    const int row0 = blockIdx.x * 64;
    const int ty = t >> 4, tx = t & 15;
    const int lrow = t >> 2, lk = (t & 3) << 2;
    const int bkk = t >> 4, bcol = (t & 15) << 2;

    float4 av = make_float4(0.f, 0.f, 0.f, 0.f);
    {
        int r = row0 + lrow;
        if (r < n) av = *reinterpret_cast<const float4*>(&agg[(size_t)r * 128 + lk]);
    }
    float4 bv = *reinterpret_cast<const float4*>(&B[(size_t)bkk * 64 + bcol]);
    As[0][lk + 0][lrow] = av.x; As[0][lk + 1][lrow] = av.y;
    As[0][lk + 2][lrow] = av.z; As[0][lk + 3][lrow] = av.w;
    *reinterpret_cast<float4*>(&Bs[0][bkk][bcol]) = bv;
    __syncthreads();

    float acc[4][4];
    #pragma unroll
    for (int i = 0; i < 4; ++i)
        #pragma unroll
        for (int j = 0; j < 4; ++j) acc[i][j] = 0.f;

    for (int kt = 0; kt < 12; ++kt) {
        const int cur = kt & 1;
        if (kt + 1 < 12) {
            int k0 = (kt + 1) << 4;
            int r = row0 + lrow;
            int kk = k0 + lk;
            av = make_float4(0.f, 0.f, 0.f, 0.f);
            if (r < n)
                av = (kk < 128)
                    ? *reinterpret_cast<const float4*>(&agg[(size_t)r * 128 + kk])
                    : *reinterpret_cast<const float4*>(&in[(size_t)r * 64 + (kk - 128)]);
            bv = *reinterpret_cast<const float4*>(&B[(size_t)(k0 + bkk) * 64 + bcol]);
        }
        #pragma unroll
        for (int kk = 0; kk < 16; ++kk) {
            float4 a4 = *reinterpret_cast<const float4*>(&As[cur][kk][ty << 2]);
            float4 b4 = *reinterpret_cast<const float4*>(&Bs[cur][kk][tx << 2]);
            float aa[4] = {a4.x, a4.y, a4.z, a4.w};
            float bb[4] = {b4.x, b4.y, b4.z, b4.w};
            #pragma unroll
            for (int i = 0; i < 4; ++i)
                #pragma unroll
                for (int j = 0; j < 4; ++j)
                    acc[i][j] = fmaf(aa[i], bb[j], acc[i][j]);
        }
        if (kt + 1 < 12) {
            const int nx = cur ^ 1;
            As[nx][lk + 0][lrow] = av.x; As[nx][lk + 1][lrow] = av.y;
            As[nx][lk + 2][lrow] = av.z; As[nx][lk + 3][lrow] = av.w;
            *reinterpret_cast<float4*>(&Bs[nx][bkk][bcol]) = bv;
        }
        __syncthreads();
    }

    float4 bia = *reinterpret_cast<const float4*>(&bias[tx << 2]);
    #pragma unroll
    for (int i = 0; i < 4; ++i) {
        int r = row0 + (ty << 2) + i;
        if (r >= n) continue;
        size_t idx = (size_t)r * 64 + (tx << 2);
        float4 v = make_float4(acc[i][0] + bia.x, acc[i][1] + bia.y,
                               acc[i][2] + bia.z, acc[i][3] + bia.w);
        if (mode == 0) {
            *reinterpret_cast<float4*>(&u_out[idx]) = v;
        } else {
            float4 ai = make_float4(0.f, 0.f, 0.f, 0.f);
            if (acc_in) ai = *reinterpret_cast<const float4*>(&acc_in[idx]);
            float4 an = make_float4(ai.x + c3 * v.x, ai.y + c3 * v.y,
                                    ai.z + c3 * v.z, ai.w + c3 * v.w);
            *reinterpret_cast<float4*>(&acc_out[idx]) = an;
            float4 hb = *reinterpret_cast<const float4*>(&hbuf[idx]);
            float4 to = make_float4(hb.x + c1 * v.x + c2 * an.x,
                                    hb.y + c1 * v.y + c2 * an.y,
                                    hb.z + c1 * v.z + c2 * an.z,
                                    hb.w + c1 * v.w + c2 * an.w);
            *reinterpret_cast<float4*>(&t_out[idx]) = to;
        }
    }
}

// ---------------------------------------------------------------------------
// conv1 GEMM v3: 64-row x 192-col tile, 128 threads, micro 8x12.
// LDS reads per k-step: 5 (A 2 + B 3) per 96 FMAs = 19:1 (vs 12:1 at 4x12,
// 8:1 at 2x12) — attacks the measured per-CU LDS-issue bound (4 SIMDs share
// one LDS pipe). Grid stays 782 fine-grained blocks; VGPR ~135 is free since
// grid limits occupancy. Same k-order per output -> bitwise identical.
// ---------------------------------------------------------------------------
__global__ __launch_bounds__(128) void conv1_gemm_v3(const float* __restrict__ x,
                                                     const float* __restrict__ B,
                                                     int n, float* __restrict__ yz,
                                                     float* __restrict__ base,
                                                     const float* __restrict__ b1) {
    __shared__ __align__(16) float As[16][68];
    __shared__ __align__(16) float Bs[16][200];
    const int t = threadIdx.x;
    const int row0 = blockIdx.x * 64;
    const int ty = t >> 4, tx = t & 15;   // ty 0..7 (8 rows each), tx 0..15
    const int bkk0 = t >> 4, bcol = (t & 15) << 2;
    float acc[8][12];
    #pragma unroll
    for (int i = 0; i < 8; ++i)
        #pragma unroll
        for (int j = 0; j < 12; ++j) acc[i][j] = 0.f;

    for (int kt = 0; kt < 16; ++kt) {
        int k0 = kt << 4;
        // A: 64 rows x 16 k = 256 quads; 128 threads x 2
        #pragma unroll
        for (int hh = 0; hh < 2; ++hh) {
            int q = t + 128 * hh;
            int row = q >> 2;
            int lkq = (q & 3) << 2;
            float4 av = make_float4(0.f, 0.f, 0.f, 0.f);
            int r = row0 + row;
            if (r < n)
                av = *reinterpret_cast<const float4*>(&x[(size_t)r * 256 + k0 + lkq]);
            As[lkq + 0][row] = av.x; As[lkq + 1][row] = av.y;
            As[lkq + 2][row] = av.z; As[lkq + 3][row] = av.w;
        }
        // B: 16 k x 192 cols; thread covers kk = bkk0 and bkk0+8, 3 quads each
        #pragma unroll
        for (int hh = 0; hh < 2; ++hh) {
            int kk = bkk0 + 8 * hh;
            const float* bp = &B[(size_t)(k0 + kk) * 192 + bcol];
            *reinterpret_cast<float4*>(&Bs[kk][bcol])       = *reinterpret_cast<const float4*>(bp);
            *reinterpret_cast<float4*>(&Bs[kk][bcol + 64])  = *reinterpret_cast<const float4*>(bp + 64);
            *reinterpret_cast<float4*>(&Bs[kk][bcol + 128]) = *reinterpret_cast<const float4*>(bp + 128);
        }
        __syncthreads();
        #pragma unroll
        for (int kk = 0; kk < 16; ++kk) {
            float4 a0 = *reinterpret_cast<const float4*>(&As[kk][ty << 3]);
            float4 a1 = *reinterpret_cast<const float4*>(&As[kk][(ty << 3) + 4]);
            float4 b0 = *reinterpret_cast<const float4*>(&Bs[kk][tx << 2]);
            float4 b1q = *reinterpret_cast<const float4*>(&Bs[kk][(tx << 2) + 64]);
            float4 b2q = *reinterpret_cast<const float4*>(&Bs[kk][(tx << 2) + 128]);
            float aa[8] = {a0.x, a0.y, a0.z, a0.w, a1.x, a1.y, a1.z, a1.w};
            float bb[12] = {b0.x, b0.y, b0.z, b0.w, b1q.x, b1q.y, b1q.z, b1q.w,
                            b2q.x, b2q.y, b2q.z, b2q.w};
            #pragma unroll
            for (int i = 0; i < 8; ++i)
                #pragma unroll
                for (int j = 0; j < 12; ++j)
                    acc[i][j] = fmaf(aa[i], bb[j], acc[i][j]);
        }
        __syncthreads();
    }

    float4 bb4 = *reinterpret_cast<const float4*>(&b1[tx << 2]);
    #pragma unroll
    for (int i = 0; i < 8; ++i) {
        int r = row0 + (ty << 3) + i;
        if (r >= n) continue;
        float4 q0 = make_float4(acc[i][0], acc[i][1], acc[i][2], acc[i][3]);
        float4 q1 = make_float4(acc[i][4], acc[i][5], acc[i][6], acc[i][7]);
        float4 q2 = make_float4(acc[i][8] + bb4.x, acc[i][9] + bb4.y,
                                acc[i][10] + bb4.z, acc[i][11] + bb4.w);
        *reinterpret_cast<float4*>(&yz[(size_t)r * 128 + (tx << 2)]) = q0;
        *reinterpret_cast<float4*>(&yz[(size_t)r * 128 + 64 + (tx << 2)]) = q1;
        *reinterpret_cast<float4*>(&base[(size_t)r * 64 + (tx << 2)]) = q2;
    }
}

// ---------------------------------------------------------------------------
// conv1 edge transform (8 lanes/node x 8 ch)
// ---------------------------------------------------------------------------
__global__ __launch_bounds__(256) void edge_tf64_v8(const float* __restrict__ yz,
                                                    const int* __restrict__ rowp,
                                                    const int* __restrict__ es,
                                                    const float* __restrict__ ep,
                                                    const float* __restrict__ invd,
                                                    const float* __restrict__ base,
                                                    float* __restrict__ out, int n) {
    int gid = blockIdx.x * 256 + threadIdx.x;
    int node = gid >> 3;
    if (node >= n) return;
    int c8 = (gid & 7) << 3;
    int e = rowp[node], eend = rowp[node + 1];
    float a[8] = {0.f, 0.f, 0.f, 0.f, 0.f, 0.f, 0.f, 0.f};
    for (; e + 2 <= eend; e += 2) {
        int s0 = es[e], s1 = es[e + 1];
        float p0 = ep[e], p1 = ep[e + 1];
        float4 y0a = *reinterpret_cast<const float4*>(&yz[(size_t)s0 * 128 + c8]);
        float4 y0b = *reinterpret_cast<const float4*>(&yz[(size_t)s0 * 128 + c8 + 4]);
        float4 z0a = *reinterpret_cast<const float4*>(&yz[(size_t)s0 * 128 + 64 + c8]);
        float4 z0b = *reinterpret_cast<const float4*>(&yz[(size_t)s0 * 128 + 64 + c8 + 4]);
        float4 y1a = *reinterpret_cast<const float4*>(&yz[(size_t)s1 * 128 + c8]);
        float4 y1b = *reinterpret_cast<const float4*>(&yz[(size_t)s1 * 128 + c8 + 4]);
        float4 z1a = *reinterpret_cast<const float4*>(&yz[(size_t)s1 * 128 + 64 + c8]);
        float4 z1b = *reinterpret_cast<const float4*>(&yz[(size_t)s1 * 128 + 64 + c8 + 4]);
        const float* ya0 = &y0a.x; const float* yb0 = &y0b.x;
        const float* za0 = &z0a.x; const float* zb0 = &z0b.x;
        const float* ya1 = &y1a.x; const float* yb1 = &y1b.x;
        const float* za1 = &z1a.x; const float* zb1 = &z1b.x;
        #pragma unroll
        for (int j = 0; j < 4; ++j) {
            a[j]     += fmaf(p0, za0[j] - ya0[j], ya0[j]) + fmaf(p1, za1[j] - ya1[j], ya1[j]);
            a[4 + j] += fmaf(p0, zb0[j] - yb0[j], yb0[j]) + fmaf(p1, zb1[j] - yb1[j], yb1[j]);
        }
    }
    for (; e < eend; ++e) {
        int s = es[e];
        float pe = ep[e];
        float4 ya = *reinterpret_cast<const float4*>(&yz[(size_t)s * 128 + c8]);
        float4 yb = *reinterpret_cast<const float4*>(&yz[(size_t)s * 128 + c8 + 4]);
        float4 za = *reinterpret_cast<const float4*>(&yz[(size_t)s * 128 + 64 + c8]);
        float4 zb = *reinterpret_cast<const float4*>(&yz[(size_t)s * 128 + 64 + c8 + 4]);
        const float* fy = &ya.x; const float* gy = &yb.x;
        const float* fz = &za.x; const float* gz = &zb.x;
        #pragma unroll
        for (int j = 0; j < 4; ++j) {
            a[j]     += fmaf(pe, fz[j] - fy[j], fy[j]);
            a[4 + j] += fmaf(pe, gz[j] - gy[j], gy[j]);
        }
    }
    float w = invd[node];
    size_t idx = (size_t)node * 64 + c8;
    float4 ba = *reinterpret_cast<const float4*>(&base[idx]);
    float4 bbv = *reinterpret_cast<const float4*>(&base[idx + 4]);
    float4 o0 = make_float4(tanhf(fmaf(a[0], w, ba.x)), tanhf(fmaf(a[1], w, ba.y)),
                            tanhf(fmaf(a[2], w, ba.z)), tanhf(fmaf(a[3], w, ba.w)));
    float4 o1 = make_float4(tanhf(fmaf(a[4], w, bbv.x)), tanhf(fmaf(a[5], w, bbv.y)),
                            tanhf(fmaf(a[6], w, bbv.z)), tanhf(fmaf(a[7], w, bbv.w)));
    *reinterpret_cast<float4*>(&out[idx]) = o0;
    *reinterpret_cast<float4*>(&out[idx + 4]) = o1;
}

__global__ __launch_bounds__(256) void edge_tf16_lsm(const float* __restrict__ yz,
                                                     const int* __restrict__ rowp,
                                                     const int* __restrict__ es,
                                                     const float* __restrict__ ep,
                                                     const float* __restrict__ invd,
                                                     const float* __restrict__ base,
                                                     float* __restrict__ out, int n) {
    int gid = blockIdx.x * 256 + threadIdx.x;
    int node = gid >> 4;
    if (node >= n) return;
    int c = gid & 15;
    int e = rowp[node], eend = rowp[node + 1];
    float a = 0.f;
    for (; e + 4 <= eend; e += 4) {
        int s0 = es[e], s1 = es[e + 1], s2 = es[e + 2], s3 = es[e + 3];
        float p0 = ep[e], p1 = ep[e + 1], p2 = ep[e + 2], p3 = ep[e + 3];
        float y0 = yz[(size_t)s0 * 32 + c],      z0 = yz[(size_t)s0 * 32 + 16 + c];
        float y1 = yz[(size_t)s1 * 32 + c],      z1 = yz[(size_t)s1 * 32 + 16 + c];
        float y2 = yz[(size_t)s2 * 32 + c],      z2 = yz[(size_t)s2 * 32 + 16 + c];
        float y3 = yz[(size_t)s3 * 32 + c],      z3 = yz[(size_t)s3 * 32 + 16 + c];
        a += fmaf(p0, z0 - y0, y0);
        a += fmaf(p1, z1 - y1, y1);
        a += fmaf(p2, z2 - y2, y2);
        a += fmaf(p3, z3 - y3, y3);
    }
    for (; e < eend; ++e) {
        int s = es[e]; float pe = ep[e];
        float y = yz[(size_t)s * 32 + c], z = yz[(size_t)s * 32 + 16 + c];
        a += fmaf(pe, z - y, y);
    }
    float o = tanhf(a * invd[node] + base[(size_t)node * 16 + c]);
    float m = o;
    #pragma unroll
    for (int off = 8; off >= 1; off >>= 1) m = fmaxf(m, __shfl_xor(m, off, 16));
    float ex = expf(o - m);
    float s = ex;
    #pragma unroll
    for (int off = 8; off >= 1; off >>= 1) s += __shfl_xor(s, off, 16);
    out[(size_t)node * 16 + c] = (o - m) - logf(s);
}

// ---------------------------------------------------------------------------
// conv2 GEMM (K=64, M=48)
// ---------------------------------------------------------------------------
__global__ __launch_bounds__(256) void gemm_tiled(
    const float* __restrict__ A0, int lda0, int K0,
    const float* __restrict__ A1, int lda1,
    const float* __restrict__ B,
    int n, int K, int M,
    float* __restrict__ out0, int w0, const float* __restrict__ bias0,
    float* __restrict__ out1, int w1, const float* __restrict__ bias1,
    int split) {
    __shared__ __align__(16) float As[16][68];
    __shared__ __align__(16) float Bs[16][68];
    const int t = threadIdx.x;
    const int row0 = blockIdx.x * 64;
    const int col0 = blockIdx.y * 64;
    const int ty = t >> 4, tx = t & 15;
    const int lrow = t >> 2, lk = (t & 3) << 2;
    const int bkk = t >> 4, bcol = (t & 15) << 2;
    float acc[4][4];
    #pragma unroll
    for (int i = 0; i < 4; ++i)
        #pragma unroll
        for (int j = 0; j < 4; ++j) acc[i][j] = 0.f;

    for (int k0 = 0; k0 < K; k0 += 16) {
        float4 av = make_float4(0.f, 0.f, 0.f, 0.f);
        {
            int r = row0 + lrow;
            if (r < n) {
                int kk = k0 + lk;
                const float* src = (kk < K0)
                    ? (A0 + (size_t)r * lda0 + kk)
                    : (A1 + (size_t)r * lda1 + (kk - K0));
                av = *reinterpret_cast<const float4*>(src);
            }
        }
        float4 bv = make_float4(0.f, 0.f, 0.f, 0.f);
        {
            int c = col0 + bcol;
            int kk = k0 + bkk;
            if (c < M) bv = *reinterpret_cast<const float4*>(B + (size_t)kk * M + c);
        }
        As[lk + 0][lrow] = av.x; As[lk + 1][lrow] = av.y;
        As[lk + 2][lrow] = av.z; As[lk + 3][lrow] = av.w;
        *reinterpret_cast<float4*>(&Bs[bkk][bcol]) = bv;
        __syncthreads();
        #pragma unroll
        for (int kk = 0; kk < 16; ++kk) {
            float4 a4 = *reinterpret_cast<const float4*>(&As[kk][ty << 2]);
            float4 b4 = *reinterpret_cast<const float4*>(&Bs[kk][tx << 2]);
            float aa[4] = {a4.x, a4.y, a4.z, a4.w};
            float bb[4] = {b4.x, b4.y, b4.z, b4.w};
            #pragma unroll
            for (int i = 0; i < 4; ++i)
                #pragma unroll
                for (int j = 0; j < 4; ++j)
                    acc[i][j] = fmaf(aa[i], bb[j], acc[i][j]);
        }
        __syncthreads();
    }

    #pragma unroll
    for (int i = 0; i < 4; ++i) {
        int r = row0 + (ty << 2) + i;
        if (r >= n) continue;
        #pragma unroll
        for (int j = 0; j < 4; ++j) {
            int c = col0 + (tx << 2) + j;
            if (c >= M) continue;
            float v = acc[i][j];
            if (c < split) {
                if (bias0) v += bias0[c];
                out0[(size_t)r * w0 + c] = v;
            } else {
                int cc = c - split;
                if (bias1) v += bias1[cc];
                out1[(size_t)r * w1 + cc] = v;
            }
        }
    }
}

// ---------------------------------------------------------------------------
// Host-side launcher
// ---------------------------------------------------------------------------

static void hidden_conv(hipStream_t stream, const float* in, float* agg,
                        const int* rowp, const int* es, const float* ep,
                        const float* invd, const float* Bc, const float* bias, int n,
                        int mode, float* u_out,
                        const float* h, const float* acc_in, float* acc_out,
                        float* t_out, float c1, float c2, float c3) {
    edge_agg64_v4<<<ceil_div(n * 16, 256), 256, 0, stream>>>(in, rowp, es, ep, invd,
                                                             agg, n);
    hidden_gemm_db<<<ceil_div(n, 64), 256, 0, stream>>>(agg, in, Bc, bias, n, mode,
                                                        u_out, h, acc_in, acc_out,
                                                        t_out, c1, c2, c3);
}

extern "C" void kernel_launch(void* const* d_in, const int* in_sizes, int n_in,
                              void* d_out, int out_size, void* d_ws, size_t ws_size,
                              hipStream_t stream) {
    const float* x  = (const float*)d_in[0];
    const float* pE = (const float*)d_in[1];
    const int*   sr = (const int*)d_in[2];
    const int*   ds = (const int*)d_in[3];
    const float* W1 = (const float*)d_in[4];
    const float* R1 = (const float*)d_in[5];
    const float* b1 = (const float*)d_in[6];
    const float* Wa = (const float*)d_in[7];
    const float* Ra = (const float*)d_in[8];
    const float* ba = (const float*)d_in[9];
    const float* Wb = (const float*)d_in[10];
    const float* Rb = (const float*)d_in[11];
    const float* bb = (const float*)d_in[12];
    const float* W2 = (const float*)d_in[13];
    const float* R2 = (const float*)d_in[14];
    const float* b2 = (const float*)d_in[15];
    const int n = in_sizes[0] / 256;
    const int E = in_sizes[2];
    float* out = (float*)d_out;

    char* w = (char*)d_ws;
    auto alloc = [&](size_t bytes) -> void* {
        void* ptr = (void*)w;
        w += (bytes + 255) & ~(size_t)255;
        return ptr;
    };
    int nscan = ceil_div(n, 2048);
    int*   deg  = (int*)alloc((size_t)n * 4);
    int*   fill = (int*)alloc((size_t)n * 4);
    int*   rowp = (int*)alloc((size_t)(n + 1) * 4);
    float* invd = (float*)alloc((size_t)n * 4);
    int*   bsum = (int*)alloc((size_t)256 * 4);
    int*   ei   = (int*)alloc((size_t)E * 4);
    int*   es   = (int*)alloc((size_t)E * 4);
    float* ep   = (float*)alloc((size_t)E * 4);
    float* Bc1  = (float*)alloc((size_t)256 * 192 * 4);
    float* Bca  = (float*)alloc((size_t)192 * 64 * 4);
    float* Bcb  = (float*)alloc((size_t)192 * 64 * 4);
    float* Bc2  = (float*)alloc((size_t)64 * 48 * 4);
    float* big0 = (float*)alloc((size_t)n * 128 * 4);  // yz / agg buffer
    float* big1 = (float*)alloc((size_t)n * 64 * 4);   // base buffer
    float* h    = (float*)alloc((size_t)n * 64 * 4);
    float* u    = (float*)alloc((size_t)n * 64 * 4);
    float* tb   = (float*)alloc((size_t)n * 64 * 4);
    float* acc  = (float*)alloc((size_t)n * 64 * 4);

    const int PACK_TOTAL = 256 * 192 + 2 * 192 * 64 + 64 * 48;

    zero2<<<ceil_div(n, 256), 256, 0, stream>>>(deg, fill, n);
    pack_all<<<ceil_div(PACK_TOTAL, 256), 256, 0, stream>>>(W1, R1, Wa, Ra, Wb, Rb,
                                                            W2, R2, Bc1, Bca, Bcb, Bc2);
    hist_kernel<<<ceil_div(E, 256), 256, 0, stream>>>(ds, deg, E);
    scan_blocksum<<<nscan, 256, 0, stream>>>(deg, bsum, n);
    scan_tops<<<1, 256, 0, stream>>>(bsum, nscan);
    scan_final<<<nscan, 256, 0, stream>>>(deg, bsum, rowp, invd, n, E);
    scatter_idx<<<ceil_div(E, 256), 256, 0, stream>>>(ds, rowp, fill, ei, E);
    sort_fill<<<ceil_div(n, 256), 256, 0, stream>>>(rowp, ei, sr, pE, es, ep, n);

    // conv1: x @ [W1_0|W1_1|R1] -> yz(big0), base(big1)+b1; then edge transform
    conv1_gemm_v3<<<ceil_div(n, 64), 128, 0, stream>>>(x, Bc1, n, big0, big1, b1);
    edge_tf64_v8<<<ceil_div(n * 8, 256), 256, 0, stream>>>(big0, rowp, es, ep, invd,
                                                           big1, h, n);

    // RK4 over f(y) = conv_b(conv_a(y)), T=3
    // k1
    hidden_conv(stream, h, big0, rowp, es, ep, invd, Bca, ba, n, 0, u,
                nullptr, nullptr, nullptr, nullptr, 0.f, 0.f, 0.f);
    hidden_conv(stream, u, big0, rowp, es, ep, invd, Bcb, bb, n, 1, nullptr,
                h, nullptr, acc, tb, 1.5f, 0.f, 1.f);
    // k2
    hidden_conv(stream, tb, big0, rowp, es, ep, invd, Bca, ba, n, 0, u,
                nullptr, nullptr, nullptr, nullptr, 0.f, 0.f, 0.f);
    hidden_conv(stream, u, big0, rowp, es, ep, invd, Bcb, bb, n, 1, nullptr,
                h, acc, acc, tb, 1.5f, 0.f, 2.f);
    // k3
    hidden_conv(stream, tb, big0, rowp, es, ep, invd, Bca, ba, n, 0, u,
                nullptr, nullptr, nullptr, nullptr, 0.f, 0.f, 0.f);
    hidden_conv(stream, u, big0, rowp, es, ep, invd, Bcb, bb, n, 1, nullptr,
                h, acc, acc, tb, 3.f, 0.f, 2.f);
    // k4: t_out becomes h_new = h + 0.5*(k1+2k2+2k3+k4)
    hidden_conv(stream, tb, big0, rowp, es, ep, invd, Bca, ba, n, 0, u,
                nullptr, nullptr, nullptr, nullptr, 0.f, 0.f, 0.f);
    hidden_conv(stream, u, big0, rowp, es, ep, invd, Bcb, bb, n, 1, nullptr,
                h, acc, acc, tb, 0.f, 0.5f, 1.f);

    // conv2: h_new @ [W2_0|W2_1|R2] -> yz2(big0,w=32), base2(big1,w=16)+b2
    gemm_tiled<<<dim3(ceil_div(n, 64), 1), 256, 0, stream>>>(
        tb, 64, 64, nullptr, 0, Bc2, n, 64, 48,
        big0, 32, nullptr, big1, 16, b2, 32);
    edge_tf16_lsm<<<ceil_div(n * 16, 256), 256, 0, stream>>>(big0, rowp, es, ep, invd,
                                                             big1, out, n);
}